// Round 4
// baseline (840.610 us; speedup 1.0000x reference)
//
#include <hip/hip_runtime.h>
#include <math.h>

#define NB 64
#define NGRAPH 2000
#define EGRAPH 64000
#define NN (NB*NGRAPH)      // 128000
#define NE (NB*EGRAPH)      // 4096000
#define KSEL 1600
#define FEAT 10000
#define EMBD 64
#define G1D 32
#define G2D 32
#define DENSED 64
#define NCLSD 10

// Graph->XCD ownership: graph g lives on XCD (g>>3). Kernels touching graph
// g's data map blocks so blockIdx%8 == g>>3 (round-robin dispatch heuristic;
// perf-only, never correctness).

// ---------------------------------------------------------------------------
// K1a: degree count (dst), XCD-local chunks. deg[] zeroed via memset before.
// 250 blocks/graph x 256 edges.
// ---------------------------------------------------------------------------
__global__ __launch_bounds__(256) void deg_count(const int* __restrict__ ei,
                                                 int* __restrict__ deg)
{
    const int lb = blockIdx.x;                 // 16000 blocks
    const int xcd = lb & 7, t = lb >> 3;       // t in [0,2000)
    const int g = xcd * 8 + t / 250;
    const int chunk = t % 250;
    int e = g * EGRAPH + chunk * 256 + threadIdx.x;
    int d = ei[NE + e];
    atomicAdd(&deg[d], 1);
}

// ---------------------------------------------------------------------------
// K1b: per-graph exclusive scan of degrees -> row_start; dinv; deg becomes
//      the global scatter cursor (in-place). one block per graph.
// ---------------------------------------------------------------------------
__global__ __launch_bounds__(256) void scan_graph(int* __restrict__ deg,
                                                  float* __restrict__ dinv,
                                                  int* __restrict__ row_start)
{
    __shared__ int hist[NGRAPH];
    __shared__ int csA[256];
    __shared__ int csB[256];
    const int b = (blockIdx.x & 7) * 8 + (blockIdx.x >> 3);   // XCD-local graph
    const int tid = threadIdx.x;
    const int base_n = b * NGRAPH, base_e = b * EGRAPH;

    for (int v = tid; v < NGRAPH; v += 256) {
        int c = deg[base_n + v];
        hist[v] = c;
        dinv[base_n + v] = rsqrtf((float)(c + 1));   // +1 self-loop
    }
    __syncthreads();
    if (tid < 250) {
        int s = 0;
        #pragma unroll
        for (int i = 0; i < 8; ++i) s += hist[tid * 8 + i];
        csA[tid] = s;
    }
    __syncthreads();
    int* sb = csA; int* db = csB;
    for (int off = 1; off < 256; off <<= 1) {
        int v = 0;
        if (tid < 250) { v = sb[tid]; if (tid >= off) v += sb[tid - off]; }
        if (tid < 250) db[tid] = v;
        __syncthreads();
        int* t = sb; sb = db; db = t;
    }
    if (tid < 250) {
        int run = (tid == 0) ? 0 : sb[tid - 1];
        #pragma unroll
        for (int i = 0; i < 8; ++i) {
            int idx = tid * 8 + i;
            int c = hist[idx];
            row_start[base_n + idx] = base_e + run;
            deg[base_n + idx] = base_e + run;    // global cursor
            run += c;
        }
    }
}

// ---------------------------------------------------------------------------
// K1c: scatter src into CSR slots, XCD-local (cursor + csr slice stay in the
// owning XCD's L2). 250 blocks/graph x 256 edges.
// ---------------------------------------------------------------------------
__global__ __launch_bounds__(256) void scatter_csr(const int* __restrict__ ei,
                                                   int* __restrict__ cursor,
                                                   int* __restrict__ csr)
{
    const int lb = blockIdx.x;                 // 16000 blocks
    const int xcd = lb & 7, t = lb >> 3;       // t in [0,2000)
    const int g = xcd * 8 + t / 250;
    const int chunk = t % 250;
    int e = g * EGRAPH + chunk * 256 + threadIdx.x;
    int s = ei[e];
    int d = ei[NE + e];
    int pos = atomicAdd(&cursor[d], 1);
    csr[pos] = s;
}

// ---------------------------------------------------------------------------
// K2: embW = emb @ W1   (10000x64 @ 64x32)
// ---------------------------------------------------------------------------
__global__ __launch_bounds__(256) void embw_kernel(const float* __restrict__ emb,
                                                   const float* __restrict__ W1,
                                                   float* __restrict__ embW)
{
    __shared__ float W1s[EMBD * G1D];
    for (int i = threadIdx.x; i < EMBD * G1D; i += 256) W1s[i] = W1[i];
    __syncthreads();
    int id = blockIdx.x * 256 + threadIdx.x;
    int r = id >> 5, c = id & 31;
    if (r >= FEAT) return;
    const float* er = emb + r * EMBD;
    float acc = 0.f;
    #pragma unroll 8
    for (int k = 0; k < EMBD; ++k) acc += er[k] * W1s[k * G1D + c];
    embW[r * G1D + c] = acc;
}

// ---------------------------------------------------------------------------
// K3: A'[v] = dinv[v] * embW[x[v]]   (float4 lanes: 8 lanes per node)
// ---------------------------------------------------------------------------
__global__ __launch_bounds__(256) void gather_kernel(const int* __restrict__ x,
                                                     const float* __restrict__ embW,
                                                     const float* __restrict__ dinv,
                                                     float* __restrict__ A)
{
    int id = blockIdx.x * 256 + threadIdx.x;   // id = v*8 + r
    int v = id >> 3, r = id & 7;
    int xv = x[v];
    float dv = dinv[v];
    float4 e = ((const float4*)(embW + (size_t)xv * G1D))[r];
    e.x *= dv; e.y *= dv; e.z *= dv; e.w *= dv;
    ((float4*)(A + (size_t)v * G1D))[r] = e;
}

// ---------------------------------------------------------------------------
// agg common structure: half-wave (32 lanes) per node, 4 edge-slots x 8 lanes
// x float4. XCD swizzle: blockIdx%8 selects XCD -> graphs [xcd*8, xcd*8+8).
// ---------------------------------------------------------------------------

// K4: layer-1 aggregation + ReLU + (h1 @ W2) * dinv -> B'
__global__ __launch_bounds__(256) void agg1_kernel(const float* __restrict__ Ain,
                                                   const float* __restrict__ dinv,
                                                   const int* __restrict__ row_start,
                                                   const int* __restrict__ csr,
                                                   const float* __restrict__ b1,
                                                   const float* __restrict__ W2,
                                                   float* __restrict__ Bout)
{
    __shared__ float W2s[G1D * G2D];
    for (int i = threadIdx.x; i < G1D * G2D; i += 256) W2s[i] = W2[i];
    __syncthreads();
    const int lb = blockIdx.x;
    const int xcd = lb & 7, idx = lb >> 3;
    const int b = xcd * 8 + (idx >> 5);     // graph
    const int blk = idx & 31;
    const int half = threadIdx.x >> 5;      // 0..7
    const int hl = threadIdx.x & 31;        // lane in half-wave
    const int slot = hl >> 3;               // 0..3 edge slot
    const int r = hl & 7;                   // column quad: cols 4r..4r+3
    const int base_n = b * NGRAPH;
    const float4 bias4 = ((const float4*)b1)[r];

    for (int i = 0; i < 8; ++i) {
        int vloc = blk * 64 + half * 8 + i;
        if (vloc >= NGRAPH) break;
        int v = base_n + vloc;
        int rs = row_start[v];
        int re = (v == NN - 1) ? NE : row_start[v + 1];
        float4 acc = make_float4(0.f, 0.f, 0.f, 0.f);
        if (slot == 0)
            acc = ((const float4*)(Ain + (size_t)v * G1D))[r];   // self-loop
        int j = rs + slot;
        int s = (j < re) ? csr[j] : 0;
        while (j < re) {
            int jn = j + 4;
            int sn = (jn < re) ? csr[jn] : 0;     // prefetch next index
            float4 a = ((const float4*)(Ain + (size_t)s * G1D))[r];
            acc.x += a.x; acc.y += a.y; acc.z += a.z; acc.w += a.w;
            j = jn; s = sn;
        }
        #pragma unroll
        for (int off = 8; off <= 16; off <<= 1) {
            acc.x += __shfl_xor(acc.x, off, 32);
            acc.y += __shfl_xor(acc.y, off, 32);
            acc.z += __shfl_xor(acc.z, off, 32);
            acc.w += __shfl_xor(acc.w, off, 32);
        }
        float dv = dinv[v];
        float4 h4;
        h4.x = fmaxf(dv * acc.x + bias4.x, 0.f);
        h4.y = fmaxf(dv * acc.y + bias4.y, 0.f);
        h4.z = fmaxf(dv * acc.z + bias4.z, 0.f);
        h4.w = fmaxf(dv * acc.w + bias4.w, 0.f);
        float o = 0.f;
        #pragma unroll
        for (int k = 0; k < G1D; ++k) {
            float hk;
            switch (k & 3) {
                case 0: hk = __shfl(h4.x, k >> 2, 32); break;
                case 1: hk = __shfl(h4.y, k >> 2, 32); break;
                case 2: hk = __shfl(h4.z, k >> 2, 32); break;
                default: hk = __shfl(h4.w, k >> 2, 32); break;
            }
            o += hk * W2s[k * G2D + hl];
        }
        Bout[(size_t)v * G2D + hl] = dv * o;
    }
}

// K5: layer-2 aggregation + ReLU -> h2 ; score = tanh(h2 . pw / ||pw||)
__global__ __launch_bounds__(256) void agg2_kernel(const float* __restrict__ Bin,
                                                   const float* __restrict__ dinv,
                                                   const int* __restrict__ row_start,
                                                   const int* __restrict__ csr,
                                                   const float* __restrict__ b2,
                                                   const float* __restrict__ pool_w,
                                                   float* __restrict__ h2out,
                                                   float* __restrict__ scores)
{
    const int lb = blockIdx.x;
    const int xcd = lb & 7, idx = lb >> 3;
    const int b = xcd * 8 + (idx >> 5);
    const int blk = idx & 31;
    const int half = threadIdx.x >> 5;
    const int hl = threadIdx.x & 31;
    const int slot = hl >> 3;
    const int r = hl & 7;
    const int base_n = b * NGRAPH;
    const float4 bias4 = ((const float4*)b2)[r];
    const float4 pw4 = ((const float4*)pool_w)[r];

    float pw = pool_w[hl];
    float nsq = pw * pw;
    #pragma unroll
    for (int off = 16; off; off >>= 1) nsq += __shfl_xor(nsq, off, 32);
    const float inv_norm = rsqrtf(nsq);

    for (int i = 0; i < 8; ++i) {
        int vloc = blk * 64 + half * 8 + i;
        if (vloc >= NGRAPH) break;
        int v = base_n + vloc;
        int rs = row_start[v];
        int re = (v == NN - 1) ? NE : row_start[v + 1];
        float4 acc = make_float4(0.f, 0.f, 0.f, 0.f);
        if (slot == 0)
            acc = ((const float4*)(Bin + (size_t)v * G2D))[r];
        int j = rs + slot;
        int s = (j < re) ? csr[j] : 0;
        while (j < re) {
            int jn = j + 4;
            int sn = (jn < re) ? csr[jn] : 0;
            float4 a = ((const float4*)(Bin + (size_t)s * G2D))[r];
            acc.x += a.x; acc.y += a.y; acc.z += a.z; acc.w += a.w;
            j = jn; s = sn;
        }
        #pragma unroll
        for (int off = 8; off <= 16; off <<= 1) {
            acc.x += __shfl_xor(acc.x, off, 32);
            acc.y += __shfl_xor(acc.y, off, 32);
            acc.z += __shfl_xor(acc.z, off, 32);
            acc.w += __shfl_xor(acc.w, off, 32);
        }
        float dv = dinv[v];
        float4 h4;
        h4.x = fmaxf(dv * acc.x + bias4.x, 0.f);
        h4.y = fmaxf(dv * acc.y + bias4.y, 0.f);
        h4.z = fmaxf(dv * acc.z + bias4.z, 0.f);
        h4.w = fmaxf(dv * acc.w + bias4.w, 0.f);
        if (slot == 0)
            ((float4*)(h2out + (size_t)v * G2D))[r] = h4;
        float t = h4.x * pw4.x + h4.y * pw4.y + h4.z * pw4.z + h4.w * pw4.w;
        t += __shfl_xor(t, 1, 32);
        t += __shfl_xor(t, 2, 32);
        t += __shfl_xor(t, 4, 32);
        if (hl == 0) scores[v] = tanhf(t * inv_norm);
    }
}

// ---------------------------------------------------------------------------
// K6: per-graph top-K(1600 of 2000) + scaled-gather max-pool + dense MLP
// one block per graph, 256 threads (XCD-local graph mapping)
// ---------------------------------------------------------------------------
__global__ __launch_bounds__(256) void topk_pool_mlp(const float* __restrict__ h2,
                                                     const float* __restrict__ scores,
                                                     const float* __restrict__ dense_W,
                                                     const float* __restrict__ dense_b,
                                                     const float* __restrict__ out_W,
                                                     const float* __restrict__ out_b,
                                                     float* __restrict__ out)
{
    __shared__ unsigned keys[NGRAPH];
    __shared__ float    sval[NGRAPH];
    __shared__ unsigned char inc[NGRAPH];
    __shared__ int  redc[4];
    __shared__ float red[8][32];
    __shared__ float gvec[32];
    __shared__ float dvec[DENSED];
    const int b = (blockIdx.x & 7) * 8 + (blockIdx.x >> 3);   // XCD-local graph
    const int tid = threadIdx.x;
    const int base_n = b * NGRAPH;

    for (int v = tid; v < NGRAPH; v += 256) {
        float f = scores[base_n + v];
        sval[v] = f;
        unsigned u = __float_as_uint(f);
        keys[v] = (u & 0x80000000u) ? ~u : (u | 0x80000000u);
    }
    __syncthreads();

    const int wid = tid >> 6, ln = tid & 63;
    unsigned T = 0;
    for (int bit = 31; bit >= 0; --bit) {
        unsigned cand = T | (1u << bit);
        int c = 0;
        for (int v = tid; v < NGRAPH; v += 256) c += (keys[v] >= cand) ? 1 : 0;
        #pragma unroll
        for (int off = 32; off; off >>= 1) c += __shfl_down(c, off, 64);
        if (ln == 0) redc[wid] = c;
        __syncthreads();
        int cnt = redc[0] + redc[1] + redc[2] + redc[3];
        if (cnt >= KSEL) T = cand;
        __syncthreads();
    }

    int cg = 0, ce = 0;
    for (int v = tid; v < NGRAPH; v += 256) {
        cg += (keys[v] > T) ? 1 : 0;
        ce += (keys[v] == T) ? 1 : 0;
    }
    int packed = (cg << 16) | ce;
    #pragma unroll
    for (int off = 32; off; off >>= 1) packed += __shfl_down(packed, off, 64);
    if (ln == 0) redc[wid] = packed;
    __syncthreads();
    int tot = redc[0] + redc[1] + redc[2] + redc[3];
    int m_gt = tot >> 16, m_eq = tot & 0xffff;
    int needed = KSEL - m_gt;
    float fT = (T & 0x80000000u) ? __uint_as_float(T & 0x7fffffffu)
                                 : __uint_as_float(~T);
    if (m_eq == needed || fT == 0.0f) {
        for (int v = tid; v < NGRAPH; v += 256) inc[v] = (keys[v] >= T) ? 1 : 0;
    } else {
        if (tid == 0) {
            int take = 0;
            for (int v = 0; v < NGRAPH; ++v) {
                unsigned k = keys[v];
                if (k > T) inc[v] = 1;
                else if (k == T && take < needed) { inc[v] = 1; ++take; }
                else inc[v] = 0;
            }
        }
    }
    __syncthreads();

    const int c = tid & 31, grp = tid >> 5;
    float m = -INFINITY;
    for (int v = grp; v < NGRAPH; v += 8) {
        if (inc[v]) m = fmaxf(m, sval[v] * h2[(size_t)(base_n + v) * G2D + c]);
    }
    red[grp][c] = m;
    __syncthreads();
    if (tid < 32) {
        float g = red[0][tid];
        #pragma unroll
        for (int rr = 1; rr < 8; ++rr) g = fmaxf(g, red[rr][tid]);
        gvec[tid] = g;
    }
    __syncthreads();
    if (tid < DENSED) {
        float t = dense_b[tid];
        #pragma unroll
        for (int k = 0; k < G2D; ++k) t += gvec[k] * dense_W[k * DENSED + tid];
        dvec[tid] = fmaxf(t, 0.f);
    }
    __syncthreads();
    if (tid < NCLSD) {
        float o = out_b[tid];
        #pragma unroll
        for (int j = 0; j < DENSED; ++j) o += dvec[j] * out_W[j * NCLSD + tid];
        out[b * NCLSD + tid] = o;
    }
}

// ---------------------------------------------------------------------------
extern "C" void kernel_launch(void* const* d_in, const int* in_sizes, int n_in,
                              void* d_out, int out_size, void* d_ws, size_t ws_size,
                              hipStream_t stream)
{
    (void)in_sizes; (void)n_in; (void)out_size; (void)ws_size;
    const int*   x       = (const int*)  d_in[0];
    const int*   edge    = (const int*)  d_in[1];
    const float* emb     = (const float*)d_in[3];
    const float* W1      = (const float*)d_in[4];
    const float* b1      = (const float*)d_in[5];
    const float* W2      = (const float*)d_in[6];
    const float* b2      = (const float*)d_in[7];
    const float* pool_w  = (const float*)d_in[8];
    const float* dense_W = (const float*)d_in[9];
    const float* dense_b = (const float*)d_in[10];
    const float* out_W   = (const float*)d_in[11];
    const float* out_b   = (const float*)d_in[12];
    float* outp = (float*)d_out;

    // workspace carve-up (~53 MB)
    float* embW      = (float*)d_ws;                 // FEAT*32
    float* Abuf      = embW + FEAT * G1D;            // N*32 (A' then h2)
    float* Bbuf      = Abuf + (size_t)NN * G1D;      // N*32 (B')
    float* dinv      = Bbuf + (size_t)NN * G2D;      // N
    int*   row_start = (int*)(dinv + NN);            // N
    int*   csr       = row_start + NN;               // E
    float* scores    = (float*)(csr + NE);           // N
    int*   deg       = (int*)(scores + NN);          // N (degree, then cursor)

    hipMemsetAsync(deg, 0, NN * sizeof(int), stream);
    deg_count<<<NE / 256, 256, 0, stream>>>(edge, deg);
    scan_graph<<<NB, 256, 0, stream>>>(deg, dinv, row_start);
    scatter_csr<<<NE / 256, 256, 0, stream>>>(edge, deg, csr);
    embw_kernel<<<(FEAT * G1D) / 256, 256, 0, stream>>>(emb, W1, embW);
    gather_kernel<<<(NN * 8) / 256, 256, 0, stream>>>(x, embW, dinv, Abuf);
    agg1_kernel<<<NB * 32, 256, 0, stream>>>(Abuf, dinv, row_start, csr, b1, W2, Bbuf);
    agg2_kernel<<<NB * 32, 256, 0, stream>>>(Bbuf, dinv, row_start, csr, b2, pool_w, Abuf, scores);
    topk_pool_mlp<<<NB, 256, 0, stream>>>(Abuf, scores, dense_W, dense_b, out_W, out_b, outp);
}

// Round 5
// 382.123 us; speedup vs baseline: 2.1998x; 2.1998x over previous
//
#include <hip/hip_runtime.h>
#include <math.h>

#define NB 64
#define NGRAPH 2000
#define EGRAPH 64000
#define NN (NB*NGRAPH)      // 128000
#define NE (NB*EGRAPH)      // 4096000
#define KSEL 1600
#define FEAT 10000
#define EMBD 64
#define G1D 32
#define G2D 32
#define DENSED 64
#define NCLSD 10
#define NCHUNK 4
#define CHUNK_E (EGRAPH/NCHUNK)   // 16000

// CSR build: 3-phase chunked counting sort, NO global atomics.
// chist/ccur live in Bbuf (16 MB), consumed before agg1 overwrites it.

// ---------------------------------------------------------------------------
// K1a: per-chunk LDS histogram of dst. 4 blocks/graph x 256 threads.
// ---------------------------------------------------------------------------
__global__ __launch_bounds__(256) void chunk_hist(const int* __restrict__ ei,
                                                  int* __restrict__ chist)
{
    __shared__ int hist[NGRAPH];
    const int blk = blockIdx.x;          // 0..255
    const int g = blk >> 2, q = blk & 3;
    const int tid = threadIdx.x;
    const int base_e = g * EGRAPH + q * CHUNK_E;
    const int base_n = g * NGRAPH;
    for (int v = tid; v < NGRAPH; v += 256) hist[v] = 0;
    __syncthreads();
    for (int k = tid; k < CHUNK_E; k += 256) {
        int d = ei[NE + base_e + k];
        atomicAdd(&hist[d - base_n], 1);      // LDS atomic
    }
    __syncthreads();
    int* out = chist + (size_t)(g * NCHUNK + q) * NGRAPH;
    for (int v = tid; v < NGRAPH; v += 256) out[v] = hist[v];
}

// ---------------------------------------------------------------------------
// K1b: per-graph: deg = sum of 4 chunk hists -> dinv; exclusive scan ->
//      row_start; per-chunk absolute cursors -> ccur. one block per graph.
// ---------------------------------------------------------------------------
__global__ __launch_bounds__(256) void scan_graph(const int* __restrict__ chist,
                                                  int* __restrict__ ccur,
                                                  float* __restrict__ dinv,
                                                  int* __restrict__ row_start)
{
    __shared__ int cs0[NGRAPH], cs1[NGRAPH], cs2[NGRAPH];
    __shared__ int hist[NGRAPH];
    __shared__ int csA[256];
    __shared__ int csB[256];
    const int b = blockIdx.x;
    const int tid = threadIdx.x;
    const int base_n = b * NGRAPH, base_e = b * EGRAPH;
    const int* ch = chist + (size_t)b * NCHUNK * NGRAPH;

    for (int v = tid; v < NGRAPH; v += 256) {
        int c0 = ch[v];
        int c1 = ch[NGRAPH + v];
        int c2 = ch[2 * NGRAPH + v];
        int c3 = ch[3 * NGRAPH + v];
        cs0[v] = c0; cs1[v] = c1; cs2[v] = c2;
        int tot = c0 + c1 + c2 + c3;
        hist[v] = tot;
        dinv[base_n + v] = rsqrtf((float)(tot + 1));   // +1 self-loop
    }
    __syncthreads();
    if (tid < 250) {
        int s = 0;
        #pragma unroll
        for (int i = 0; i < 8; ++i) s += hist[tid * 8 + i];
        csA[tid] = s;
    }
    __syncthreads();
    int* sb = csA; int* db = csB;
    for (int off = 1; off < 256; off <<= 1) {
        int v = 0;
        if (tid < 250) { v = sb[tid]; if (tid >= off) v += sb[tid - off]; }
        if (tid < 250) db[tid] = v;
        __syncthreads();
        int* t = sb; sb = db; db = t;
    }
    if (tid < 250) {
        int run = (tid == 0) ? 0 : sb[tid - 1];
        #pragma unroll
        for (int i = 0; i < 8; ++i) {
            int idx = tid * 8 + i;
            int c = hist[idx];
            hist[idx] = run;            // overwrite count with exclusive prefix
            run += c;
        }
    }
    __syncthreads();
    int* cc = ccur + (size_t)b * NCHUNK * NGRAPH;
    for (int v = tid; v < NGRAPH; v += 256) {
        int b0 = base_e + hist[v];
        row_start[base_n + v] = b0;
        int c0 = cs0[v], c1 = cs1[v], c2 = cs2[v];
        cc[v] = b0;
        cc[NGRAPH + v] = b0 + c0;
        cc[2 * NGRAPH + v] = b0 + c0 + c1;
        cc[3 * NGRAPH + v] = b0 + c0 + c1 + c2;
    }
}

// ---------------------------------------------------------------------------
// K1c: scatter src into CSR slots using private LDS cursors (no global
// atomics). 4 blocks/graph x 256 threads.
// ---------------------------------------------------------------------------
__global__ __launch_bounds__(256) void scatter_csr(const int* __restrict__ ei,
                                                   const int* __restrict__ ccur,
                                                   int* __restrict__ csr)
{
    __shared__ int cur[NGRAPH];
    const int blk = blockIdx.x;
    const int g = blk >> 2, q = blk & 3;
    const int tid = threadIdx.x;
    const int base_e = g * EGRAPH + q * CHUNK_E;
    const int base_n = g * NGRAPH;
    const int* cc = ccur + (size_t)(g * NCHUNK + q) * NGRAPH;
    for (int v = tid; v < NGRAPH; v += 256) cur[v] = cc[v];
    __syncthreads();
    for (int k = tid; k < CHUNK_E; k += 256) {
        int s = ei[base_e + k];
        int d = ei[NE + base_e + k];
        int pos = atomicAdd(&cur[d - base_n], 1);   // LDS atomic
        csr[pos] = s;
    }
}

// ---------------------------------------------------------------------------
// K2: embW = emb @ W1   (10000x64 @ 64x32)
// ---------------------------------------------------------------------------
__global__ __launch_bounds__(256) void embw_kernel(const float* __restrict__ emb,
                                                   const float* __restrict__ W1,
                                                   float* __restrict__ embW)
{
    __shared__ float W1s[EMBD * G1D];
    for (int i = threadIdx.x; i < EMBD * G1D; i += 256) W1s[i] = W1[i];
    __syncthreads();
    int id = blockIdx.x * 256 + threadIdx.x;
    int r = id >> 5, c = id & 31;
    if (r >= FEAT) return;
    const float* er = emb + r * EMBD;
    float acc = 0.f;
    #pragma unroll 8
    for (int k = 0; k < EMBD; ++k) acc += er[k] * W1s[k * G1D + c];
    embW[r * G1D + c] = acc;
}

// ---------------------------------------------------------------------------
// K3: A'[v] = dinv[v] * embW[x[v]]   (float4 lanes: 8 lanes per node)
// ---------------------------------------------------------------------------
__global__ __launch_bounds__(256) void gather_kernel(const int* __restrict__ x,
                                                     const float* __restrict__ embW,
                                                     const float* __restrict__ dinv,
                                                     float* __restrict__ A)
{
    int id = blockIdx.x * 256 + threadIdx.x;   // id = v*8 + r
    int v = id >> 3, r = id & 7;
    int xv = x[v];
    float dv = dinv[v];
    float4 e = ((const float4*)(embW + (size_t)xv * G1D))[r];
    e.x *= dv; e.y *= dv; e.z *= dv; e.w *= dv;
    ((float4*)(A + (size_t)v * G1D))[r] = e;
}

// ---------------------------------------------------------------------------
// agg common structure: half-wave (32 lanes) per node, 4 edge-slots x 8 lanes
// x float4. XCD swizzle: blockIdx%8 selects XCD -> graphs [xcd*8, xcd*8+8).
// ---------------------------------------------------------------------------

// K4: layer-1 aggregation + ReLU + (h1 @ W2) * dinv -> B'
__global__ __launch_bounds__(256) void agg1_kernel(const float* __restrict__ Ain,
                                                   const float* __restrict__ dinv,
                                                   const int* __restrict__ row_start,
                                                   const int* __restrict__ csr,
                                                   const float* __restrict__ b1,
                                                   const float* __restrict__ W2,
                                                   float* __restrict__ Bout)
{
    __shared__ float W2s[G1D * G2D];
    for (int i = threadIdx.x; i < G1D * G2D; i += 256) W2s[i] = W2[i];
    __syncthreads();
    const int lb = blockIdx.x;
    const int xcd = lb & 7, idx = lb >> 3;
    const int b = xcd * 8 + (idx >> 5);     // graph
    const int blk = idx & 31;
    const int half = threadIdx.x >> 5;      // 0..7
    const int hl = threadIdx.x & 31;        // lane in half-wave
    const int slot = hl >> 3;               // 0..3 edge slot
    const int r = hl & 7;                   // column quad: cols 4r..4r+3
    const int base_n = b * NGRAPH;
    const float4 bias4 = ((const float4*)b1)[r];

    for (int i = 0; i < 8; ++i) {
        int vloc = blk * 64 + half * 8 + i;
        if (vloc >= NGRAPH) break;
        int v = base_n + vloc;
        int rs = row_start[v];
        int re = (v == NN - 1) ? NE : row_start[v + 1];
        float4 acc = make_float4(0.f, 0.f, 0.f, 0.f);
        if (slot == 0)
            acc = ((const float4*)(Ain + (size_t)v * G1D))[r];   // self-loop
        int j = rs + slot;
        int s = (j < re) ? csr[j] : 0;
        while (j < re) {
            int jn = j + 4;
            int sn = (jn < re) ? csr[jn] : 0;     // prefetch next index
            float4 a = ((const float4*)(Ain + (size_t)s * G1D))[r];
            acc.x += a.x; acc.y += a.y; acc.z += a.z; acc.w += a.w;
            j = jn; s = sn;
        }
        #pragma unroll
        for (int off = 8; off <= 16; off <<= 1) {
            acc.x += __shfl_xor(acc.x, off, 32);
            acc.y += __shfl_xor(acc.y, off, 32);
            acc.z += __shfl_xor(acc.z, off, 32);
            acc.w += __shfl_xor(acc.w, off, 32);
        }
        float dv = dinv[v];
        float4 h4;
        h4.x = fmaxf(dv * acc.x + bias4.x, 0.f);
        h4.y = fmaxf(dv * acc.y + bias4.y, 0.f);
        h4.z = fmaxf(dv * acc.z + bias4.z, 0.f);
        h4.w = fmaxf(dv * acc.w + bias4.w, 0.f);
        float o = 0.f;
        #pragma unroll
        for (int k = 0; k < G1D; ++k) {
            float hk;
            switch (k & 3) {
                case 0: hk = __shfl(h4.x, k >> 2, 32); break;
                case 1: hk = __shfl(h4.y, k >> 2, 32); break;
                case 2: hk = __shfl(h4.z, k >> 2, 32); break;
                default: hk = __shfl(h4.w, k >> 2, 32); break;
            }
            o += hk * W2s[k * G2D + hl];
        }
        Bout[(size_t)v * G2D + hl] = dv * o;
    }
}

// K5: layer-2 aggregation + ReLU -> h2 ; score = tanh(h2 . pw / ||pw||)
__global__ __launch_bounds__(256) void agg2_kernel(const float* __restrict__ Bin,
                                                   const float* __restrict__ dinv,
                                                   const int* __restrict__ row_start,
                                                   const int* __restrict__ csr,
                                                   const float* __restrict__ b2,
                                                   const float* __restrict__ pool_w,
                                                   float* __restrict__ h2out,
                                                   float* __restrict__ scores)
{
    const int lb = blockIdx.x;
    const int xcd = lb & 7, idx = lb >> 3;
    const int b = xcd * 8 + (idx >> 5);
    const int blk = idx & 31;
    const int half = threadIdx.x >> 5;
    const int hl = threadIdx.x & 31;
    const int slot = hl >> 3;
    const int r = hl & 7;
    const int base_n = b * NGRAPH;
    const float4 bias4 = ((const float4*)b2)[r];
    const float4 pw4 = ((const float4*)pool_w)[r];

    float pw = pool_w[hl];
    float nsq = pw * pw;
    #pragma unroll
    for (int off = 16; off; off >>= 1) nsq += __shfl_xor(nsq, off, 32);
    const float inv_norm = rsqrtf(nsq);

    for (int i = 0; i < 8; ++i) {
        int vloc = blk * 64 + half * 8 + i;
        if (vloc >= NGRAPH) break;
        int v = base_n + vloc;
        int rs = row_start[v];
        int re = (v == NN - 1) ? NE : row_start[v + 1];
        float4 acc = make_float4(0.f, 0.f, 0.f, 0.f);
        if (slot == 0)
            acc = ((const float4*)(Bin + (size_t)v * G2D))[r];
        int j = rs + slot;
        int s = (j < re) ? csr[j] : 0;
        while (j < re) {
            int jn = j + 4;
            int sn = (jn < re) ? csr[jn] : 0;
            float4 a = ((const float4*)(Bin + (size_t)s * G2D))[r];
            acc.x += a.x; acc.y += a.y; acc.z += a.z; acc.w += a.w;
            j = jn; s = sn;
        }
        #pragma unroll
        for (int off = 8; off <= 16; off <<= 1) {
            acc.x += __shfl_xor(acc.x, off, 32);
            acc.y += __shfl_xor(acc.y, off, 32);
            acc.z += __shfl_xor(acc.z, off, 32);
            acc.w += __shfl_xor(acc.w, off, 32);
        }
        float dv = dinv[v];
        float4 h4;
        h4.x = fmaxf(dv * acc.x + bias4.x, 0.f);
        h4.y = fmaxf(dv * acc.y + bias4.y, 0.f);
        h4.z = fmaxf(dv * acc.z + bias4.z, 0.f);
        h4.w = fmaxf(dv * acc.w + bias4.w, 0.f);
        if (slot == 0)
            ((float4*)(h2out + (size_t)v * G2D))[r] = h4;
        float t = h4.x * pw4.x + h4.y * pw4.y + h4.z * pw4.z + h4.w * pw4.w;
        t += __shfl_xor(t, 1, 32);
        t += __shfl_xor(t, 2, 32);
        t += __shfl_xor(t, 4, 32);
        if (hl == 0) scores[v] = tanhf(t * inv_norm);
    }
}

// ---------------------------------------------------------------------------
// K6: per-graph top-K(1600 of 2000) + scaled-gather max-pool + dense MLP
// one block per graph, 256 threads
// ---------------------------------------------------------------------------
__global__ __launch_bounds__(256) void topk_pool_mlp(const float* __restrict__ h2,
                                                     const float* __restrict__ scores,
                                                     const float* __restrict__ dense_W,
                                                     const float* __restrict__ dense_b,
                                                     const float* __restrict__ out_W,
                                                     const float* __restrict__ out_b,
                                                     float* __restrict__ out)
{
    __shared__ unsigned keys[NGRAPH];
    __shared__ float    sval[NGRAPH];
    __shared__ unsigned char inc[NGRAPH];
    __shared__ int  redc[4];
    __shared__ float red[8][32];
    __shared__ float gvec[32];
    __shared__ float dvec[DENSED];
    const int b = (blockIdx.x & 7) * 8 + (blockIdx.x >> 3);   // XCD-local graph
    const int tid = threadIdx.x;
    const int base_n = b * NGRAPH;

    for (int v = tid; v < NGRAPH; v += 256) {
        float f = scores[base_n + v];
        sval[v] = f;
        unsigned u = __float_as_uint(f);
        keys[v] = (u & 0x80000000u) ? ~u : (u | 0x80000000u);
    }
    __syncthreads();

    const int wid = tid >> 6, ln = tid & 63;
    unsigned T = 0;
    for (int bit = 31; bit >= 0; --bit) {
        unsigned cand = T | (1u << bit);
        int c = 0;
        for (int v = tid; v < NGRAPH; v += 256) c += (keys[v] >= cand) ? 1 : 0;
        #pragma unroll
        for (int off = 32; off; off >>= 1) c += __shfl_down(c, off, 64);
        if (ln == 0) redc[wid] = c;
        __syncthreads();
        int cnt = redc[0] + redc[1] + redc[2] + redc[3];
        if (cnt >= KSEL) T = cand;
        __syncthreads();
    }

    int cg = 0, ce = 0;
    for (int v = tid; v < NGRAPH; v += 256) {
        cg += (keys[v] > T) ? 1 : 0;
        ce += (keys[v] == T) ? 1 : 0;
    }
    int packed = (cg << 16) | ce;
    #pragma unroll
    for (int off = 32; off; off >>= 1) packed += __shfl_down(packed, off, 64);
    if (ln == 0) redc[wid] = packed;
    __syncthreads();
    int tot = redc[0] + redc[1] + redc[2] + redc[3];
    int m_gt = tot >> 16, m_eq = tot & 0xffff;
    int needed = KSEL - m_gt;
    float fT = (T & 0x80000000u) ? __uint_as_float(T & 0x7fffffffu)
                                 : __uint_as_float(~T);
    if (m_eq == needed || fT == 0.0f) {
        for (int v = tid; v < NGRAPH; v += 256) inc[v] = (keys[v] >= T) ? 1 : 0;
    } else {
        if (tid == 0) {
            int take = 0;
            for (int v = 0; v < NGRAPH; ++v) {
                unsigned k = keys[v];
                if (k > T) inc[v] = 1;
                else if (k == T && take < needed) { inc[v] = 1; ++take; }
                else inc[v] = 0;
            }
        }
    }
    __syncthreads();

    const int c = tid & 31, grp = tid >> 5;
    float m = -INFINITY;
    for (int v = grp; v < NGRAPH; v += 8) {
        if (inc[v]) m = fmaxf(m, sval[v] * h2[(size_t)(base_n + v) * G2D + c]);
    }
    red[grp][c] = m;
    __syncthreads();
    if (tid < 32) {
        float g = red[0][tid];
        #pragma unroll
        for (int rr = 1; rr < 8; ++rr) g = fmaxf(g, red[rr][tid]);
        gvec[tid] = g;
    }
    __syncthreads();
    if (tid < DENSED) {
        float t = dense_b[tid];
        #pragma unroll
        for (int k = 0; k < G2D; ++k) t += gvec[k] * dense_W[k * DENSED + tid];
        dvec[tid] = fmaxf(t, 0.f);
    }
    __syncthreads();
    if (tid < NCLSD) {
        float o = out_b[tid];
        #pragma unroll
        for (int j = 0; j < DENSED; ++j) o += dvec[j] * out_W[j * NCLSD + tid];
        out[b * NCLSD + tid] = o;
    }
}

// ---------------------------------------------------------------------------
extern "C" void kernel_launch(void* const* d_in, const int* in_sizes, int n_in,
                              void* d_out, int out_size, void* d_ws, size_t ws_size,
                              hipStream_t stream)
{
    (void)in_sizes; (void)n_in; (void)out_size; (void)ws_size;
    const int*   x       = (const int*)  d_in[0];
    const int*   edge    = (const int*)  d_in[1];
    const float* emb     = (const float*)d_in[3];
    const float* W1      = (const float*)d_in[4];
    const float* b1      = (const float*)d_in[5];
    const float* W2      = (const float*)d_in[6];
    const float* b2      = (const float*)d_in[7];
    const float* pool_w  = (const float*)d_in[8];
    const float* dense_W = (const float*)d_in[9];
    const float* dense_b = (const float*)d_in[10];
    const float* out_W   = (const float*)d_in[11];
    const float* out_b   = (const float*)d_in[12];
    float* outp = (float*)d_out;

    // workspace carve-up (~53 MB)
    float* embW      = (float*)d_ws;                 // FEAT*32
    float* Abuf      = embW + FEAT * G1D;            // N*32 (A' then h2)
    float* Bbuf      = Abuf + (size_t)NN * G1D;      // N*32 (B')
    float* dinv      = Bbuf + (size_t)NN * G2D;      // N
    int*   row_start = (int*)(dinv + NN);            // N
    int*   csr       = row_start + NN;               // E
    float* scores    = (float*)(csr + NE);           // N

    // CSR-build scratch inside Bbuf (consumed before agg1 writes Bbuf):
    int* chist = (int*)Bbuf;                         // NB*4*NGRAPH = 512000
    int* ccur  = chist + NB * NCHUNK * NGRAPH;       // NB*4*NGRAPH = 512000

    chunk_hist<<<NB * NCHUNK, 256, 0, stream>>>(edge, chist);
    scan_graph<<<NB, 256, 0, stream>>>(chist, ccur, dinv, row_start);
    scatter_csr<<<NB * NCHUNK, 256, 0, stream>>>(edge, ccur, csr);
    embw_kernel<<<(FEAT * G1D) / 256, 256, 0, stream>>>(emb, W1, embW);
    gather_kernel<<<(NN * 8) / 256, 256, 0, stream>>>(x, embW, dinv, Abuf);
    agg1_kernel<<<NB * 32, 256, 0, stream>>>(Abuf, dinv, row_start, csr, b1, W2, Bbuf);
    agg2_kernel<<<NB * 32, 256, 0, stream>>>(Bbuf, dinv, row_start, csr, b2, pool_w, Abuf, scores);
    topk_pool_mlp<<<NB, 256, 0, stream>>>(Abuf, scores, dense_W, dense_b, out_W, out_b, outp);
}

// Round 6
// 307.691 us; speedup vs baseline: 2.7320x; 1.2419x over previous
//
#include <hip/hip_runtime.h>
#include <math.h>

#define NB 64
#define NGRAPH 2000
#define EGRAPH 64000
#define NN (NB*NGRAPH)      // 128000
#define NE (NB*EGRAPH)      // 4096000
#define KSEL 1600
#define FEAT 10000
#define EMBD 64
#define G1D 32
#define G2D 32
#define DENSED 64
#define NCLSD 10
#define NCHUNK 4
#define CHUNK_E (EGRAPH/NCHUNK)   // 16000

// CSR build: 3-phase chunked counting sort, NO global atomics.
// chist/ccur live in Bbuf (16 MB), consumed before agg1 overwrites it.

// ---------------------------------------------------------------------------
// K1a: per-chunk LDS histogram of dst. 4 blocks/graph x 256 threads.
// ---------------------------------------------------------------------------
__global__ __launch_bounds__(256) void chunk_hist(const int* __restrict__ ei,
                                                  int* __restrict__ chist)
{
    __shared__ int hist[NGRAPH];
    const int blk = blockIdx.x;          // 0..255
    const int g = blk >> 2, q = blk & 3;
    const int tid = threadIdx.x;
    const int base_e = g * EGRAPH + q * CHUNK_E;
    const int base_n = g * NGRAPH;
    for (int v = tid; v < NGRAPH; v += 256) hist[v] = 0;
    __syncthreads();
    for (int k = tid; k < CHUNK_E; k += 256) {
        int d = ei[NE + base_e + k];
        atomicAdd(&hist[d - base_n], 1);      // LDS atomic
    }
    __syncthreads();
    int* out = chist + (size_t)(g * NCHUNK + q) * NGRAPH;
    for (int v = tid; v < NGRAPH; v += 256) out[v] = hist[v];
}

// ---------------------------------------------------------------------------
// K1b: per-graph: deg = sum of 4 chunk hists -> dinv; exclusive scan ->
//      row_start; per-chunk absolute cursors -> ccur. one block per graph.
// ---------------------------------------------------------------------------
__global__ __launch_bounds__(256) void scan_graph(const int* __restrict__ chist,
                                                  int* __restrict__ ccur,
                                                  float* __restrict__ dinv,
                                                  int* __restrict__ row_start)
{
    __shared__ int cs0[NGRAPH], cs1[NGRAPH], cs2[NGRAPH];
    __shared__ int hist[NGRAPH];
    __shared__ int csA[256];
    __shared__ int csB[256];
    const int b = blockIdx.x;
    const int tid = threadIdx.x;
    const int base_n = b * NGRAPH, base_e = b * EGRAPH;
    const int* ch = chist + (size_t)b * NCHUNK * NGRAPH;

    for (int v = tid; v < NGRAPH; v += 256) {
        int c0 = ch[v];
        int c1 = ch[NGRAPH + v];
        int c2 = ch[2 * NGRAPH + v];
        int c3 = ch[3 * NGRAPH + v];
        cs0[v] = c0; cs1[v] = c1; cs2[v] = c2;
        int tot = c0 + c1 + c2 + c3;
        hist[v] = tot;
        dinv[base_n + v] = rsqrtf((float)(tot + 1));   // +1 self-loop
    }
    __syncthreads();
    if (tid < 250) {
        int s = 0;
        #pragma unroll
        for (int i = 0; i < 8; ++i) s += hist[tid * 8 + i];
        csA[tid] = s;
    }
    __syncthreads();
    int* sb = csA; int* db = csB;
    for (int off = 1; off < 256; off <<= 1) {
        int v = 0;
        if (tid < 250) { v = sb[tid]; if (tid >= off) v += sb[tid - off]; }
        if (tid < 250) db[tid] = v;
        __syncthreads();
        int* t = sb; sb = db; db = t;
    }
    if (tid < 250) {
        int run = (tid == 0) ? 0 : sb[tid - 1];
        #pragma unroll
        for (int i = 0; i < 8; ++i) {
            int idx = tid * 8 + i;
            int c = hist[idx];
            hist[idx] = run;            // overwrite count with exclusive prefix
            run += c;
        }
    }
    __syncthreads();
    int* cc = ccur + (size_t)b * NCHUNK * NGRAPH;
    for (int v = tid; v < NGRAPH; v += 256) {
        int b0 = base_e + hist[v];
        row_start[base_n + v] = b0;
        int c0 = cs0[v], c1 = cs1[v], c2 = cs2[v];
        cc[v] = b0;
        cc[NGRAPH + v] = b0 + c0;
        cc[2 * NGRAPH + v] = b0 + c0 + c1;
        cc[3 * NGRAPH + v] = b0 + c0 + c1 + c2;
    }
}

// ---------------------------------------------------------------------------
// K1c: scatter src into CSR slots using private LDS cursors (no global
// atomics). 4 blocks/graph x 256 threads.
// ---------------------------------------------------------------------------
__global__ __launch_bounds__(256) void scatter_csr(const int* __restrict__ ei,
                                                   const int* __restrict__ ccur,
                                                   int* __restrict__ csr)
{
    __shared__ int cur[NGRAPH];
    const int blk = blockIdx.x;
    const int g = blk >> 2, q = blk & 3;
    const int tid = threadIdx.x;
    const int base_e = g * EGRAPH + q * CHUNK_E;
    const int base_n = g * NGRAPH;
    const int* cc = ccur + (size_t)(g * NCHUNK + q) * NGRAPH;
    for (int v = tid; v < NGRAPH; v += 256) cur[v] = cc[v];
    __syncthreads();
    for (int k = tid; k < CHUNK_E; k += 256) {
        int s = ei[base_e + k];
        int d = ei[NE + base_e + k];
        int pos = atomicAdd(&cur[d - base_n], 1);   // LDS atomic
        csr[pos] = s;
    }
}

// ---------------------------------------------------------------------------
// K2: embW = emb @ W1   (10000x64 @ 64x32)
// ---------------------------------------------------------------------------
__global__ __launch_bounds__(256) void embw_kernel(const float* __restrict__ emb,
                                                   const float* __restrict__ W1,
                                                   float* __restrict__ embW)
{
    __shared__ float W1s[EMBD * G1D];
    for (int i = threadIdx.x; i < EMBD * G1D; i += 256) W1s[i] = W1[i];
    __syncthreads();
    int id = blockIdx.x * 256 + threadIdx.x;
    int r = id >> 5, c = id & 31;
    if (r >= FEAT) return;
    const float* er = emb + r * EMBD;
    float acc = 0.f;
    #pragma unroll 8
    for (int k = 0; k < EMBD; ++k) acc += er[k] * W1s[k * G1D + c];
    embW[r * G1D + c] = acc;
}

// ---------------------------------------------------------------------------
// K3: A'[v] = dinv[v] * embW[x[v]]   (float4 lanes: 8 lanes per node)
// ---------------------------------------------------------------------------
__global__ __launch_bounds__(256) void gather_kernel(const int* __restrict__ x,
                                                     const float* __restrict__ embW,
                                                     const float* __restrict__ dinv,
                                                     float* __restrict__ A)
{
    int id = blockIdx.x * 256 + threadIdx.x;   // id = v*8 + r
    int v = id >> 3, r = id & 7;
    int xv = x[v];
    float dv = dinv[v];
    float4 e = ((const float4*)(embW + (size_t)xv * G1D))[r];
    e.x *= dv; e.y *= dv; e.z *= dv; e.w *= dv;
    ((float4*)(A + (size_t)v * G1D))[r] = e;
}

// ---------------------------------------------------------------------------
// agg common structure: half-wave (32 lanes) per node, 4 edge-slots x 8 lanes
// x float4. XCD swizzle: blockIdx%8 selects XCD -> graphs [xcd*8, xcd*8+8).
// ---------------------------------------------------------------------------

// K4: layer-1 aggregation + ReLU + (h1 @ W2) * dinv -> B'
__global__ __launch_bounds__(256) void agg1_kernel(const float* __restrict__ Ain,
                                                   const float* __restrict__ dinv,
                                                   const int* __restrict__ row_start,
                                                   const int* __restrict__ csr,
                                                   const float* __restrict__ b1,
                                                   const float* __restrict__ W2,
                                                   float* __restrict__ Bout)
{
    __shared__ float W2s[G1D * G2D];
    for (int i = threadIdx.x; i < G1D * G2D; i += 256) W2s[i] = W2[i];
    __syncthreads();
    const int lb = blockIdx.x;
    const int xcd = lb & 7, idx = lb >> 3;
    const int b = xcd * 8 + (idx >> 5);     // graph
    const int blk = idx & 31;
    const int half = threadIdx.x >> 5;      // 0..7
    const int hl = threadIdx.x & 31;        // lane in half-wave
    const int slot = hl >> 3;               // 0..3 edge slot
    const int r = hl & 7;                   // column quad: cols 4r..4r+3
    const int base_n = b * NGRAPH;
    const float4 bias4 = ((const float4*)b1)[r];

    for (int i = 0; i < 8; ++i) {
        int vloc = blk * 64 + half * 8 + i;
        if (vloc >= NGRAPH) break;
        int v = base_n + vloc;
        int rs = row_start[v];
        int re = (v == NN - 1) ? NE : row_start[v + 1];
        float4 acc = make_float4(0.f, 0.f, 0.f, 0.f);
        if (slot == 0)
            acc = ((const float4*)(Ain + (size_t)v * G1D))[r];   // self-loop
        int j = rs + slot;
        int s = (j < re) ? csr[j] : 0;
        while (j < re) {
            int jn = j + 4;
            int sn = (jn < re) ? csr[jn] : 0;     // prefetch next index
            float4 a = ((const float4*)(Ain + (size_t)s * G1D))[r];
            acc.x += a.x; acc.y += a.y; acc.z += a.z; acc.w += a.w;
            j = jn; s = sn;
        }
        #pragma unroll
        for (int off = 8; off <= 16; off <<= 1) {
            acc.x += __shfl_xor(acc.x, off, 32);
            acc.y += __shfl_xor(acc.y, off, 32);
            acc.z += __shfl_xor(acc.z, off, 32);
            acc.w += __shfl_xor(acc.w, off, 32);
        }
        float dv = dinv[v];
        float4 h4;
        h4.x = fmaxf(dv * acc.x + bias4.x, 0.f);
        h4.y = fmaxf(dv * acc.y + bias4.y, 0.f);
        h4.z = fmaxf(dv * acc.z + bias4.z, 0.f);
        h4.w = fmaxf(dv * acc.w + bias4.w, 0.f);
        float o = 0.f;
        #pragma unroll
        for (int k = 0; k < G1D; ++k) {
            float hk;
            switch (k & 3) {
                case 0: hk = __shfl(h4.x, k >> 2, 32); break;
                case 1: hk = __shfl(h4.y, k >> 2, 32); break;
                case 2: hk = __shfl(h4.z, k >> 2, 32); break;
                default: hk = __shfl(h4.w, k >> 2, 32); break;
            }
            o += hk * W2s[k * G2D + hl];
        }
        Bout[(size_t)v * G2D + hl] = dv * o;
    }
}

// K5: layer-2 aggregation + ReLU -> h2 ; score = tanh(h2 . pw / ||pw||)
__global__ __launch_bounds__(256) void agg2_kernel(const float* __restrict__ Bin,
                                                   const float* __restrict__ dinv,
                                                   const int* __restrict__ row_start,
                                                   const int* __restrict__ csr,
                                                   const float* __restrict__ b2,
                                                   const float* __restrict__ pool_w,
                                                   float* __restrict__ h2out,
                                                   float* __restrict__ scores)
{
    const int lb = blockIdx.x;
    const int xcd = lb & 7, idx = lb >> 3;
    const int b = xcd * 8 + (idx >> 5);
    const int blk = idx & 31;
    const int half = threadIdx.x >> 5;
    const int hl = threadIdx.x & 31;
    const int slot = hl >> 3;
    const int r = hl & 7;
    const int base_n = b * NGRAPH;
    const float4 bias4 = ((const float4*)b2)[r];
    const float4 pw4 = ((const float4*)pool_w)[r];

    float pw = pool_w[hl];
    float nsq = pw * pw;
    #pragma unroll
    for (int off = 16; off; off >>= 1) nsq += __shfl_xor(nsq, off, 32);
    const float inv_norm = rsqrtf(nsq);

    for (int i = 0; i < 8; ++i) {
        int vloc = blk * 64 + half * 8 + i;
        if (vloc >= NGRAPH) break;
        int v = base_n + vloc;
        int rs = row_start[v];
        int re = (v == NN - 1) ? NE : row_start[v + 1];
        float4 acc = make_float4(0.f, 0.f, 0.f, 0.f);
        if (slot == 0)
            acc = ((const float4*)(Bin + (size_t)v * G2D))[r];
        int j = rs + slot;
        int s = (j < re) ? csr[j] : 0;
        while (j < re) {
            int jn = j + 4;
            int sn = (jn < re) ? csr[jn] : 0;
            float4 a = ((const float4*)(Bin + (size_t)s * G2D))[r];
            acc.x += a.x; acc.y += a.y; acc.z += a.z; acc.w += a.w;
            j = jn; s = sn;
        }
        #pragma unroll
        for (int off = 8; off <= 16; off <<= 1) {
            acc.x += __shfl_xor(acc.x, off, 32);
            acc.y += __shfl_xor(acc.y, off, 32);
            acc.z += __shfl_xor(acc.z, off, 32);
            acc.w += __shfl_xor(acc.w, off, 32);
        }
        float dv = dinv[v];
        float4 h4;
        h4.x = fmaxf(dv * acc.x + bias4.x, 0.f);
        h4.y = fmaxf(dv * acc.y + bias4.y, 0.f);
        h4.z = fmaxf(dv * acc.z + bias4.z, 0.f);
        h4.w = fmaxf(dv * acc.w + bias4.w, 0.f);
        if (slot == 0)
            ((float4*)(h2out + (size_t)v * G2D))[r] = h4;
        float t = h4.x * pw4.x + h4.y * pw4.y + h4.z * pw4.z + h4.w * pw4.w;
        t += __shfl_xor(t, 1, 32);
        t += __shfl_xor(t, 2, 32);
        t += __shfl_xor(t, 4, 32);
        if (hl == 0) scores[v] = tanhf(t * inv_norm);
    }
}

// ---------------------------------------------------------------------------
// K6: per-graph top-K(1600 of 2000) via 4-pass radix-256 select + parallel
// scaled max-pool + dense MLP. one block per graph, 256 threads.
// ---------------------------------------------------------------------------
__global__ __launch_bounds__(256) void topk_pool_mlp(const float* __restrict__ h2,
                                                     const float* __restrict__ scores,
                                                     const float* __restrict__ dense_W,
                                                     const float* __restrict__ dense_b,
                                                     const float* __restrict__ out_W,
                                                     const float* __restrict__ out_b,
                                                     float* __restrict__ out)
{
    __shared__ unsigned keys[NGRAPH];
    __shared__ float    sval[NGRAPH];
    __shared__ unsigned char inc[NGRAPH];
    __shared__ int  hist[256];
    __shared__ int  csA[256];
    __shared__ int  csB[256];
    __shared__ int  sel[2];              // [0]=d*, [1]=count strictly above d*
    __shared__ int  redc[4];
    __shared__ float redf[32][32];
    __shared__ float gvec[32];
    __shared__ float dvec[DENSED];
    const int b = (blockIdx.x & 7) * 8 + (blockIdx.x >> 3);   // XCD-local graph
    const int tid = threadIdx.x;
    const int base_n = b * NGRAPH;

    for (int v = tid; v < NGRAPH; v += 256) {
        float f = scores[base_n + v];
        sval[v] = f;
        unsigned u = __float_as_uint(f);
        keys[v] = (u & 0x80000000u) ? ~u : (u | 0x80000000u);  // monotone map
    }
    __syncthreads();

    // ---- radix-256 selection of K-th largest key: 4 passes, 8 bits each ----
    unsigned T = 0;
    int need = KSEL;
    #pragma unroll
    for (int pass = 0; pass < 4; ++pass) {
        const int s = 24 - pass * 8;
        const unsigned hi_mask = (pass == 0) ? 0u : (0xFFFFFFFFu << (s + 8));
        hist[tid] = 0;
        __syncthreads();
        for (int v = tid; v < NGRAPH; v += 256) {
            unsigned k = keys[v];
            if ((k & hi_mask) == (T & hi_mask))
                atomicAdd(&hist[(k >> s) & 255], 1);
        }
        __syncthreads();
        // inclusive prefix scan of reversed hist -> suffix sums
        csA[tid] = hist[255 - tid];
        __syncthreads();
        int* sb = csA; int* db = csB;
        for (int off = 1; off < 256; off <<= 1) {
            int val = sb[tid];
            if (tid >= off) val += sb[tid - off];
            db[tid] = val;
            __syncthreads();
            int* t = sb; sb = db; db = t;
        }
        // suf[d] = sb[255-d]; d* = max d with suf[d] >= need
        {
            const int d = tid;
            int suf_d = sb[255 - d];
            int suf_d1 = (d == 255) ? 0 : sb[254 - d];
            if (suf_d >= need && suf_d1 < need) {
                sel[0] = d;
                sel[1] = suf_d1;      // elements strictly above byte d
            }
        }
        __syncthreads();
        T |= ((unsigned)sel[0]) << s;
        need -= sel[1];
        __syncthreads();
    }

    // ---- tie handling (same semantics as before) ----
    const int wid = tid >> 6, ln = tid & 63;
    int cg = 0, ce = 0;
    for (int v = tid; v < NGRAPH; v += 256) {
        cg += (keys[v] > T) ? 1 : 0;
        ce += (keys[v] == T) ? 1 : 0;
    }
    int packed = (cg << 16) | ce;
    #pragma unroll
    for (int off = 32; off; off >>= 1) packed += __shfl_down(packed, off, 64);
    if (ln == 0) redc[wid] = packed;
    __syncthreads();
    int tot = redc[0] + redc[1] + redc[2] + redc[3];
    int m_gt = tot >> 16, m_eq = tot & 0xffff;
    int needed = KSEL - m_gt;
    float fT = (T & 0x80000000u) ? __uint_as_float(T & 0x7fffffffu)
                                 : __uint_as_float(~T);
    if (m_eq == needed || fT == 0.0f) {
        // unique cutoff multiplicity, or ties at exactly 0 (contribute 0*h2=0)
        for (int v = tid; v < NGRAPH; v += 256) inc[v] = (keys[v] >= T) ? 1 : 0;
    } else {
        if (tid == 0) {
            int take = 0;
            for (int v = 0; v < NGRAPH; ++v) {
                unsigned k = keys[v];
                if (k > T) inc[v] = 1;
                else if (k == T && take < needed) { inc[v] = 1; ++take; }
                else inc[v] = 0;
            }
        }
    }
    __syncthreads();

    // ---- pooled max: g[c] = max_{v in sel} score[v]*h2[v][c], parallel ----
    {
        const int rowslot = tid >> 3;       // 0..31
        const int c4 = tid & 7;             // float4 column
        float4 m4 = make_float4(-INFINITY, -INFINITY, -INFINITY, -INFINITY);
        for (int v = rowslot; v < NGRAPH; v += 32) {
            float4 hrow = ((const float4*)(h2 + (size_t)(base_n + v) * G2D))[c4];
            float sv = inc[v] ? sval[v] : 0.f;
            float big = inc[v] ? 0.f : -INFINITY;   // excluded -> -INF
            m4.x = fmaxf(m4.x, sv * hrow.x + big);
            m4.y = fmaxf(m4.y, sv * hrow.y + big);
            m4.z = fmaxf(m4.z, sv * hrow.z + big);
            m4.w = fmaxf(m4.w, sv * hrow.w + big);
        }
        redf[rowslot][c4 * 4 + 0] = m4.x;
        redf[rowslot][c4 * 4 + 1] = m4.y;
        redf[rowslot][c4 * 4 + 2] = m4.z;
        redf[rowslot][c4 * 4 + 3] = m4.w;
    }
    __syncthreads();
    if (tid < 32) {
        float g = redf[0][tid];
        #pragma unroll
        for (int rr = 1; rr < 32; ++rr) g = fmaxf(g, redf[rr][tid]);
        gvec[tid] = g;
    }
    __syncthreads();
    if (tid < DENSED) {
        float t = dense_b[tid];
        #pragma unroll
        for (int k = 0; k < G2D; ++k) t += gvec[k] * dense_W[k * DENSED + tid];
        dvec[tid] = fmaxf(t, 0.f);
    }
    __syncthreads();
    if (tid < NCLSD) {
        float o = out_b[tid];
        #pragma unroll
        for (int j = 0; j < DENSED; ++j) o += dvec[j] * out_W[j * NCLSD + tid];
        out[b * NCLSD + tid] = o;
    }
}

// ---------------------------------------------------------------------------
extern "C" void kernel_launch(void* const* d_in, const int* in_sizes, int n_in,
                              void* d_out, int out_size, void* d_ws, size_t ws_size,
                              hipStream_t stream)
{
    (void)in_sizes; (void)n_in; (void)out_size; (void)ws_size;
    const int*   x       = (const int*)  d_in[0];
    const int*   edge    = (const int*)  d_in[1];
    const float* emb     = (const float*)d_in[3];
    const float* W1      = (const float*)d_in[4];
    const float* b1      = (const float*)d_in[5];
    const float* W2      = (const float*)d_in[6];
    const float* b2      = (const float*)d_in[7];
    const float* pool_w  = (const float*)d_in[8];
    const float* dense_W = (const float*)d_in[9];
    const float* dense_b = (const float*)d_in[10];
    const float* out_W   = (const float*)d_in[11];
    const float* out_b   = (const float*)d_in[12];
    float* outp = (float*)d_out;

    // workspace carve-up (~53 MB)
    float* embW      = (float*)d_ws;                 // FEAT*32
    float* Abuf      = embW + FEAT * G1D;            // N*32 (A' then h2)
    float* Bbuf      = Abuf + (size_t)NN * G1D;      // N*32 (B')
    float* dinv      = Bbuf + (size_t)NN * G2D;      // N
    int*   row_start = (int*)(dinv + NN);            // N
    int*   csr       = row_start + NN;               // E
    float* scores    = (float*)(csr + NE);           // N

    // CSR-build scratch inside Bbuf (consumed before agg1 writes Bbuf):
    int* chist = (int*)Bbuf;                         // NB*4*NGRAPH = 512000
    int* ccur  = chist + NB * NCHUNK * NGRAPH;       // NB*4*NGRAPH = 512000

    chunk_hist<<<NB * NCHUNK, 256, 0, stream>>>(edge, chist);
    scan_graph<<<NB, 256, 0, stream>>>(chist, ccur, dinv, row_start);
    scatter_csr<<<NB * NCHUNK, 256, 0, stream>>>(edge, ccur, csr);
    embw_kernel<<<(FEAT * G1D) / 256, 256, 0, stream>>>(emb, W1, embW);
    gather_kernel<<<(NN * 8) / 256, 256, 0, stream>>>(x, embW, dinv, Abuf);
    agg1_kernel<<<NB * 32, 256, 0, stream>>>(Abuf, dinv, row_start, csr, b1, W2, Bbuf);
    agg2_kernel<<<NB * 32, 256, 0, stream>>>(Bbuf, dinv, row_start, csr, b2, pool_w, Abuf, scores);
    topk_pool_mlp<<<NB, 256, 0, stream>>>(Abuf, scores, dense_W, dense_b, out_W, out_b, outp);
}

// Round 7
// 294.492 us; speedup vs baseline: 2.8544x; 1.0448x over previous
//
#include <hip/hip_runtime.h>
#include <math.h>

#define NB 64
#define NGRAPH 2000
#define EGRAPH 64000
#define NN (NB*NGRAPH)      // 128000
#define NE (NB*EGRAPH)      // 4096000
#define KSEL 1600
#define FEAT 10000
#define EMBD 64
#define G1D 32
#define G2D 32
#define DENSED 64
#define NCLSD 10
#define NCHUNK 4
#define CHUNK_E (EGRAPH/NCHUNK)   // 16000

// CSR build: 3-phase chunked counting sort, NO global atomics.
// chist/ccur live in Bbuf (16 MB), consumed before agg1 overwrites it.
// Graph->XCD ownership: graph g lives on XCD (g>>3); every kernel touching
// graph g's data maps blocks so blockIdx%8 == g>>3 (perf-only heuristic).

// ---------------------------------------------------------------------------
// K1a: per-chunk LDS histogram of dst. 4 blocks/graph x 256 threads.
// ---------------------------------------------------------------------------
__global__ __launch_bounds__(256) void chunk_hist(const int* __restrict__ ei,
                                                  int* __restrict__ chist)
{
    __shared__ int hist[NGRAPH];
    const int lb = blockIdx.x;           // 256 blocks
    const int xcd = lb & 7, t = lb >> 3; // t in [0,32)
    const int g = xcd * 8 + (t >> 2);
    const int q = t & 3;
    const int tid = threadIdx.x;
    const int base_e = g * EGRAPH + q * CHUNK_E;
    const int base_n = g * NGRAPH;
    for (int v = tid; v < NGRAPH; v += 256) hist[v] = 0;
    __syncthreads();
    for (int k = tid; k < CHUNK_E; k += 256) {
        int d = ei[NE + base_e + k];
        atomicAdd(&hist[d - base_n], 1);      // LDS atomic
    }
    __syncthreads();
    int* out = chist + (size_t)(g * NCHUNK + q) * NGRAPH;
    for (int v = tid; v < NGRAPH; v += 256) out[v] = hist[v];
}

// ---------------------------------------------------------------------------
// K1b: per-graph: deg = sum of 4 chunk hists -> dinv; exclusive scan ->
//      row_start; per-chunk absolute cursors -> ccur. one block per graph.
// ---------------------------------------------------------------------------
__global__ __launch_bounds__(256) void scan_graph(const int* __restrict__ chist,
                                                  int* __restrict__ ccur,
                                                  float* __restrict__ dinv,
                                                  int* __restrict__ row_start)
{
    __shared__ int cs0[NGRAPH], cs1[NGRAPH], cs2[NGRAPH];
    __shared__ int hist[NGRAPH];
    __shared__ int csA[256];
    __shared__ int csB[256];
    const int b = (blockIdx.x & 7) * 8 + (blockIdx.x >> 3);   // XCD-local graph
    const int tid = threadIdx.x;
    const int base_n = b * NGRAPH, base_e = b * EGRAPH;
    const int* ch = chist + (size_t)b * NCHUNK * NGRAPH;

    for (int v = tid; v < NGRAPH; v += 256) {
        int c0 = ch[v];
        int c1 = ch[NGRAPH + v];
        int c2 = ch[2 * NGRAPH + v];
        int c3 = ch[3 * NGRAPH + v];
        cs0[v] = c0; cs1[v] = c1; cs2[v] = c2;
        int tot = c0 + c1 + c2 + c3;
        hist[v] = tot;
        dinv[base_n + v] = rsqrtf((float)(tot + 1));   // +1 self-loop
    }
    __syncthreads();
    if (tid < 250) {
        int s = 0;
        #pragma unroll
        for (int i = 0; i < 8; ++i) s += hist[tid * 8 + i];
        csA[tid] = s;
    }
    __syncthreads();
    int* sb = csA; int* db = csB;
    for (int off = 1; off < 256; off <<= 1) {
        int v = 0;
        if (tid < 250) { v = sb[tid]; if (tid >= off) v += sb[tid - off]; }
        if (tid < 250) db[tid] = v;
        __syncthreads();
        int* t = sb; sb = db; db = t;
    }
    if (tid < 250) {
        int run = (tid == 0) ? 0 : sb[tid - 1];
        #pragma unroll
        for (int i = 0; i < 8; ++i) {
            int idx = tid * 8 + i;
            int c = hist[idx];
            hist[idx] = run;            // overwrite count with exclusive prefix
            run += c;
        }
    }
    __syncthreads();
    int* cc = ccur + (size_t)b * NCHUNK * NGRAPH;
    for (int v = tid; v < NGRAPH; v += 256) {
        int b0 = base_e + hist[v];
        row_start[base_n + v] = b0;
        int c0 = cs0[v], c1 = cs1[v], c2 = cs2[v];
        cc[v] = b0;
        cc[NGRAPH + v] = b0 + c0;
        cc[2 * NGRAPH + v] = b0 + c0 + c1;
        cc[3 * NGRAPH + v] = b0 + c0 + c1 + c2;
    }
}

// ---------------------------------------------------------------------------
// K1c: scatter src into CSR slots using private LDS cursors (no global
// atomics). 4 blocks/graph x 256 threads, XCD-local so the graph's 256 KB
// csr slice fills whole lines in one L2 before writeback.
// ---------------------------------------------------------------------------
__global__ __launch_bounds__(256) void scatter_csr(const int* __restrict__ ei,
                                                   const int* __restrict__ ccur,
                                                   int* __restrict__ csr)
{
    __shared__ int cur[NGRAPH];
    const int lb = blockIdx.x;
    const int xcd = lb & 7, t = lb >> 3;
    const int g = xcd * 8 + (t >> 2);
    const int q = t & 3;
    const int tid = threadIdx.x;
    const int base_e = g * EGRAPH + q * CHUNK_E;
    const int base_n = g * NGRAPH;
    const int* cc = ccur + (size_t)(g * NCHUNK + q) * NGRAPH;
    for (int v = tid; v < NGRAPH; v += 256) cur[v] = cc[v];
    __syncthreads();
    for (int k = tid; k < CHUNK_E; k += 256) {
        int s = ei[base_e + k];
        int d = ei[NE + base_e + k];
        int pos = atomicAdd(&cur[d - base_n], 1);   // LDS atomic
        csr[pos] = s;
    }
}

// ---------------------------------------------------------------------------
// K2: embW = emb @ W1   (10000x64 @ 64x32)
// ---------------------------------------------------------------------------
__global__ __launch_bounds__(256) void embw_kernel(const float* __restrict__ emb,
                                                   const float* __restrict__ W1,
                                                   float* __restrict__ embW)
{
    __shared__ float W1s[EMBD * G1D];
    for (int i = threadIdx.x; i < EMBD * G1D; i += 256) W1s[i] = W1[i];
    __syncthreads();
    int id = blockIdx.x * 256 + threadIdx.x;
    int r = id >> 5, c = id & 31;
    if (r >= FEAT) return;
    const float* er = emb + r * EMBD;
    float acc = 0.f;
    #pragma unroll 8
    for (int k = 0; k < EMBD; ++k) acc += er[k] * W1s[k * G1D + c];
    embW[r * G1D + c] = acc;
}

// ---------------------------------------------------------------------------
// K3: A'[v] = dinv[v] * embW[x[v]]   (float4 lanes: 8 lanes per node)
// ---------------------------------------------------------------------------
__global__ __launch_bounds__(256) void gather_kernel(const int* __restrict__ x,
                                                     const float* __restrict__ embW,
                                                     const float* __restrict__ dinv,
                                                     float* __restrict__ A)
{
    int id = blockIdx.x * 256 + threadIdx.x;   // id = v*8 + r
    int v = id >> 3, r = id & 7;
    int xv = x[v];
    float dv = dinv[v];
    float4 e = ((const float4*)(embW + (size_t)xv * G1D))[r];
    e.x *= dv; e.y *= dv; e.z *= dv; e.w *= dv;
    ((float4*)(A + (size_t)v * G1D))[r] = e;
}

// ---------------------------------------------------------------------------
// agg common structure: half-wave (32 lanes) per node, 4 edge-slots x 8 lanes
// x float4. XCD swizzle: blockIdx%8 selects XCD -> graphs [xcd*8, xcd*8+8).
// ---------------------------------------------------------------------------

// K4: layer-1 aggregation + ReLU + (h1 @ W2) * dinv -> B'
__global__ __launch_bounds__(256) void agg1_kernel(const float* __restrict__ Ain,
                                                   const float* __restrict__ dinv,
                                                   const int* __restrict__ row_start,
                                                   const int* __restrict__ csr,
                                                   const float* __restrict__ b1,
                                                   const float* __restrict__ W2,
                                                   float* __restrict__ Bout)
{
    __shared__ float W2s[G1D * G2D];
    for (int i = threadIdx.x; i < G1D * G2D; i += 256) W2s[i] = W2[i];
    __syncthreads();
    const int lb = blockIdx.x;
    const int xcd = lb & 7, idx = lb >> 3;
    const int b = xcd * 8 + (idx >> 5);     // graph
    const int blk = idx & 31;
    const int half = threadIdx.x >> 5;      // 0..7
    const int hl = threadIdx.x & 31;        // lane in half-wave
    const int slot = hl >> 3;               // 0..3 edge slot
    const int r = hl & 7;                   // column quad: cols 4r..4r+3
    const int base_n = b * NGRAPH;
    const float4 bias4 = ((const float4*)b1)[r];

    for (int i = 0; i < 8; ++i) {
        int vloc = blk * 64 + half * 8 + i;
        if (vloc >= NGRAPH) break;
        int v = base_n + vloc;
        int rs = row_start[v];
        int re = (v == NN - 1) ? NE : row_start[v + 1];
        float4 acc = make_float4(0.f, 0.f, 0.f, 0.f);
        if (slot == 0)
            acc = ((const float4*)(Ain + (size_t)v * G1D))[r];   // self-loop
        int j = rs + slot;
        int s = (j < re) ? csr[j] : 0;
        while (j < re) {
            int jn = j + 4;
            int sn = (jn < re) ? csr[jn] : 0;     // prefetch next index
            float4 a = ((const float4*)(Ain + (size_t)s * G1D))[r];
            acc.x += a.x; acc.y += a.y; acc.z += a.z; acc.w += a.w;
            j = jn; s = sn;
        }
        #pragma unroll
        for (int off = 8; off <= 16; off <<= 1) {
            acc.x += __shfl_xor(acc.x, off, 32);
            acc.y += __shfl_xor(acc.y, off, 32);
            acc.z += __shfl_xor(acc.z, off, 32);
            acc.w += __shfl_xor(acc.w, off, 32);
        }
        float dv = dinv[v];
        float4 h4;
        h4.x = fmaxf(dv * acc.x + bias4.x, 0.f);
        h4.y = fmaxf(dv * acc.y + bias4.y, 0.f);
        h4.z = fmaxf(dv * acc.z + bias4.z, 0.f);
        h4.w = fmaxf(dv * acc.w + bias4.w, 0.f);
        float o = 0.f;
        #pragma unroll
        for (int k = 0; k < G1D; ++k) {
            float hk;
            switch (k & 3) {
                case 0: hk = __shfl(h4.x, k >> 2, 32); break;
                case 1: hk = __shfl(h4.y, k >> 2, 32); break;
                case 2: hk = __shfl(h4.z, k >> 2, 32); break;
                default: hk = __shfl(h4.w, k >> 2, 32); break;
            }
            o += hk * W2s[k * G2D + hl];
        }
        Bout[(size_t)v * G2D + hl] = dv * o;
    }
}

// K5: layer-2 aggregation + ReLU -> h2 ; score = tanh(h2 . pw / ||pw||)
__global__ __launch_bounds__(256) void agg2_kernel(const float* __restrict__ Bin,
                                                   const float* __restrict__ dinv,
                                                   const int* __restrict__ row_start,
                                                   const int* __restrict__ csr,
                                                   const float* __restrict__ b2,
                                                   const float* __restrict__ pool_w,
                                                   float* __restrict__ h2out,
                                                   float* __restrict__ scores)
{
    const int lb = blockIdx.x;
    const int xcd = lb & 7, idx = lb >> 3;
    const int b = xcd * 8 + (idx >> 5);
    const int blk = idx & 31;
    const int half = threadIdx.x >> 5;
    const int hl = threadIdx.x & 31;
    const int slot = hl >> 3;
    const int r = hl & 7;
    const int base_n = b * NGRAPH;
    const float4 bias4 = ((const float4*)b2)[r];
    const float4 pw4 = ((const float4*)pool_w)[r];

    float pw = pool_w[hl];
    float nsq = pw * pw;
    #pragma unroll
    for (int off = 16; off; off >>= 1) nsq += __shfl_xor(nsq, off, 32);
    const float inv_norm = rsqrtf(nsq);

    for (int i = 0; i < 8; ++i) {
        int vloc = blk * 64 + half * 8 + i;
        if (vloc >= NGRAPH) break;
        int v = base_n + vloc;
        int rs = row_start[v];
        int re = (v == NN - 1) ? NE : row_start[v + 1];
        float4 acc = make_float4(0.f, 0.f, 0.f, 0.f);
        if (slot == 0)
            acc = ((const float4*)(Bin + (size_t)v * G2D))[r];
        int j = rs + slot;
        int s = (j < re) ? csr[j] : 0;
        while (j < re) {
            int jn = j + 4;
            int sn = (jn < re) ? csr[jn] : 0;
            float4 a = ((const float4*)(Bin + (size_t)s * G2D))[r];
            acc.x += a.x; acc.y += a.y; acc.z += a.z; acc.w += a.w;
            j = jn; s = sn;
        }
        #pragma unroll
        for (int off = 8; off <= 16; off <<= 1) {
            acc.x += __shfl_xor(acc.x, off, 32);
            acc.y += __shfl_xor(acc.y, off, 32);
            acc.z += __shfl_xor(acc.z, off, 32);
            acc.w += __shfl_xor(acc.w, off, 32);
        }
        float dv = dinv[v];
        float4 h4;
        h4.x = fmaxf(dv * acc.x + bias4.x, 0.f);
        h4.y = fmaxf(dv * acc.y + bias4.y, 0.f);
        h4.z = fmaxf(dv * acc.z + bias4.z, 0.f);
        h4.w = fmaxf(dv * acc.w + bias4.w, 0.f);
        if (slot == 0)
            ((float4*)(h2out + (size_t)v * G2D))[r] = h4;
        float t = h4.x * pw4.x + h4.y * pw4.y + h4.z * pw4.z + h4.w * pw4.w;
        t += __shfl_xor(t, 1, 32);
        t += __shfl_xor(t, 2, 32);
        t += __shfl_xor(t, 4, 32);
        if (hl == 0) scores[v] = tanhf(t * inv_norm);
    }
}

// ---------------------------------------------------------------------------
// K6: per-graph top-K(1600 of 2000) via 4-pass radix-256 select + parallel
// scaled max-pool + dense MLP. one block per graph, 256 threads.
// ---------------------------------------------------------------------------
__global__ __launch_bounds__(256) void topk_pool_mlp(const float* __restrict__ h2,
                                                     const float* __restrict__ scores,
                                                     const float* __restrict__ dense_W,
                                                     const float* __restrict__ dense_b,
                                                     const float* __restrict__ out_W,
                                                     const float* __restrict__ out_b,
                                                     float* __restrict__ out)
{
    __shared__ unsigned keys[NGRAPH];
    __shared__ float    sval[NGRAPH];
    __shared__ unsigned char inc[NGRAPH];
    __shared__ int  hist[256];
    __shared__ int  csA[256];
    __shared__ int  csB[256];
    __shared__ int  sel[2];              // [0]=d*, [1]=count strictly above d*
    __shared__ int  redc[4];
    __shared__ float redf[32][32];
    __shared__ float gvec[32];
    __shared__ float dvec[DENSED];
    const int b = (blockIdx.x & 7) * 8 + (blockIdx.x >> 3);   // XCD-local graph
    const int tid = threadIdx.x;
    const int base_n = b * NGRAPH;

    for (int v = tid; v < NGRAPH; v += 256) {
        float f = scores[base_n + v];
        sval[v] = f;
        unsigned u = __float_as_uint(f);
        keys[v] = (u & 0x80000000u) ? ~u : (u | 0x80000000u);  // monotone map
    }
    __syncthreads();

    // ---- radix-256 selection of K-th largest key: 4 passes, 8 bits each ----
    unsigned T = 0;
    int need = KSEL;
    #pragma unroll
    for (int pass = 0; pass < 4; ++pass) {
        const int s = 24 - pass * 8;
        const unsigned hi_mask = (pass == 0) ? 0u : (0xFFFFFFFFu << (s + 8));
        hist[tid] = 0;
        __syncthreads();
        for (int v = tid; v < NGRAPH; v += 256) {
            unsigned k = keys[v];
            if ((k & hi_mask) == (T & hi_mask))
                atomicAdd(&hist[(k >> s) & 255], 1);
        }
        __syncthreads();
        // inclusive prefix scan of reversed hist -> suffix sums
        csA[tid] = hist[255 - tid];
        __syncthreads();
        int* sb = csA; int* db = csB;
        for (int off = 1; off < 256; off <<= 1) {
            int val = sb[tid];
            if (tid >= off) val += sb[tid - off];
            db[tid] = val;
            __syncthreads();
            int* t = sb; sb = db; db = t;
        }
        // suf[d] = sb[255-d]; d* = max d with suf[d] >= need
        {
            const int d = tid;
            int suf_d = sb[255 - d];
            int suf_d1 = (d == 255) ? 0 : sb[254 - d];
            if (suf_d >= need && suf_d1 < need) {
                sel[0] = d;
                sel[1] = suf_d1;      // elements strictly above byte d
            }
        }
        __syncthreads();
        T |= ((unsigned)sel[0]) << s;
        need -= sel[1];
        __syncthreads();
    }

    // ---- tie handling (same semantics as before) ----
    const int wid = tid >> 6, ln = tid & 63;
    int cg = 0, ce = 0;
    for (int v = tid; v < NGRAPH; v += 256) {
        cg += (keys[v] > T) ? 1 : 0;
        ce += (keys[v] == T) ? 1 : 0;
    }
    int packed = (cg << 16) | ce;
    #pragma unroll
    for (int off = 32; off; off >>= 1) packed += __shfl_down(packed, off, 64);
    if (ln == 0) redc[wid] = packed;
    __syncthreads();
    int tot = redc[0] + redc[1] + redc[2] + redc[3];
    int m_gt = tot >> 16, m_eq = tot & 0xffff;
    int needed = KSEL - m_gt;
    float fT = (T & 0x80000000u) ? __uint_as_float(T & 0x7fffffffu)
                                 : __uint_as_float(~T);
    if (m_eq == needed || fT == 0.0f) {
        // unique cutoff multiplicity, or ties at exactly 0 (contribute 0*h2=0)
        for (int v = tid; v < NGRAPH; v += 256) inc[v] = (keys[v] >= T) ? 1 : 0;
    } else {
        if (tid == 0) {
            int take = 0;
            for (int v = 0; v < NGRAPH; ++v) {
                unsigned k = keys[v];
                if (k > T) inc[v] = 1;
                else if (k == T && take < needed) { inc[v] = 1; ++take; }
                else inc[v] = 0;
            }
        }
    }
    __syncthreads();

    // ---- pooled max: g[c] = max_{v in sel} score[v]*h2[v][c], parallel ----
    {
        const int rowslot = tid >> 3;       // 0..31
        const int c4 = tid & 7;             // float4 column
        float4 m4 = make_float4(-INFINITY, -INFINITY, -INFINITY, -INFINITY);
        for (int v = rowslot; v < NGRAPH; v += 32) {
            float4 hrow = ((const float4*)(h2 + (size_t)(base_n + v) * G2D))[c4];
            float sv = inc[v] ? sval[v] : 0.f;
            float big = inc[v] ? 0.f : -INFINITY;   // excluded -> -INF
            m4.x = fmaxf(m4.x, sv * hrow.x + big);
            m4.y = fmaxf(m4.y, sv * hrow.y + big);
            m4.z = fmaxf(m4.z, sv * hrow.z + big);
            m4.w = fmaxf(m4.w, sv * hrow.w + big);
        }
        redf[rowslot][c4 * 4 + 0] = m4.x;
        redf[rowslot][c4 * 4 + 1] = m4.y;
        redf[rowslot][c4 * 4 + 2] = m4.z;
        redf[rowslot][c4 * 4 + 3] = m4.w;
    }
    __syncthreads();
    if (tid < 32) {
        float g = redf[0][tid];
        #pragma unroll
        for (int rr = 1; rr < 32; ++rr) g = fmaxf(g, redf[rr][tid]);
        gvec[tid] = g;
    }
    __syncthreads();
    if (tid < DENSED) {
        float t = dense_b[tid];
        #pragma unroll
        for (int k = 0; k < G2D; ++k) t += gvec[k] * dense_W[k * DENSED + tid];
        dvec[tid] = fmaxf(t, 0.f);
    }
    __syncthreads();
    if (tid < NCLSD) {
        float o = out_b[tid];
        #pragma unroll
        for (int j = 0; j < DENSED; ++j) o += dvec[j] * out_W[j * NCLSD + tid];
        out[b * NCLSD + tid] = o;
    }
}

// ---------------------------------------------------------------------------
extern "C" void kernel_launch(void* const* d_in, const int* in_sizes, int n_in,
                              void* d_out, int out_size, void* d_ws, size_t ws_size,
                              hipStream_t stream)
{
    (void)in_sizes; (void)n_in; (void)out_size; (void)ws_size;
    const int*   x       = (const int*)  d_in[0];
    const int*   edge    = (const int*)  d_in[1];
    const float* emb     = (const float*)d_in[3];
    const float* W1      = (const float*)d_in[4];
    const float* b1      = (const float*)d_in[5];
    const float* W2      = (const float*)d_in[6];
    const float* b2      = (const float*)d_in[7];
    const float* pool_w  = (const float*)d_in[8];
    const float* dense_W = (const float*)d_in[9];
    const float* dense_b = (const float*)d_in[10];
    const float* out_W   = (const float*)d_in[11];
    const float* out_b   = (const float*)d_in[12];
    float* outp = (float*)d_out;

    // workspace carve-up (~53 MB)
    float* embW      = (float*)d_ws;                 // FEAT*32
    float* Abuf      = embW + FEAT * G1D;            // N*32 (A' then h2)
    float* Bbuf      = Abuf + (size_t)NN * G1D;      // N*32 (B')
    float* dinv      = Bbuf + (size_t)NN * G2D;      // N
    int*   row_start = (int*)(dinv + NN);            // N
    int*   csr       = row_start + NN;               // E
    float* scores    = (float*)(csr + NE);           // N

    // CSR-build scratch inside Bbuf (consumed before agg1 writes Bbuf):
    int* chist = (int*)Bbuf;                         // NB*4*NGRAPH = 512000
    int* ccur  = chist + NB * NCHUNK * NGRAPH;       // NB*4*NGRAPH = 512000

    chunk_hist<<<NB * NCHUNK, 256, 0, stream>>>(edge, chist);
    scan_graph<<<NB, 256, 0, stream>>>(chist, ccur, dinv, row_start);
    scatter_csr<<<NB * NCHUNK, 256, 0, stream>>>(edge, ccur, csr);
    embw_kernel<<<(FEAT * G1D) / 256, 256, 0, stream>>>(emb, W1, embW);
    gather_kernel<<<(NN * 8) / 256, 256, 0, stream>>>(x, embW, dinv, Abuf);
    agg1_kernel<<<NB * 32, 256, 0, stream>>>(Abuf, dinv, row_start, csr, b1, W2, Bbuf);
    agg2_kernel<<<NB * 32, 256, 0, stream>>>(Bbuf, dinv, row_start, csr, b2, pool_w, Abuf, scores);
    topk_pool_mlp<<<NB, 256, 0, stream>>>(Abuf, scores, dense_W, dense_b, out_W, out_b, outp);
}

// Round 8
// 279.399 us; speedup vs baseline: 3.0086x; 1.0540x over previous
//
#include <hip/hip_runtime.h>
#include <math.h>

#define NB 64
#define NGRAPH 2000
#define EGRAPH 64000
#define NN (NB*NGRAPH)      // 128000
#define NE (NB*EGRAPH)      // 4096000
#define KSEL 1600
#define FEAT 10000
#define EMBD 64
#define G1D 32
#define G2D 32
#define DENSED 64
#define NCLSD 10
#define NCHUNK 4
#define CHUNK_E (EGRAPH/NCHUNK)   // 16000

// CSR build: 3-phase chunked counting sort, NO global atomics.
// chist/ccur live in Bbuf (16 MB), consumed before agg1 overwrites it.
// Graph->XCD ownership: graph g lives on XCD (g>>3); every kernel touching
// graph g's data maps blocks so blockIdx%8 == g>>3 (perf-only heuristic).

// ---------------------------------------------------------------------------
// K1a: per-chunk LDS histogram of dst. 4 blocks/graph x 256 threads.
// ---------------------------------------------------------------------------
__global__ __launch_bounds__(256) void chunk_hist(const int* __restrict__ ei,
                                                  int* __restrict__ chist)
{
    __shared__ int hist[NGRAPH];
    const int lb = blockIdx.x;           // 256 blocks
    const int xcd = lb & 7, t = lb >> 3; // t in [0,32)
    const int g = xcd * 8 + (t >> 2);
    const int q = t & 3;
    const int tid = threadIdx.x;
    const int base_e = g * EGRAPH + q * CHUNK_E;
    const int base_n = g * NGRAPH;
    for (int v = tid; v < NGRAPH; v += 256) hist[v] = 0;
    __syncthreads();
    for (int k = tid; k < CHUNK_E; k += 256) {
        int d = ei[NE + base_e + k];
        atomicAdd(&hist[d - base_n], 1);      // LDS atomic
    }
    __syncthreads();
    int* out = chist + (size_t)(g * NCHUNK + q) * NGRAPH;
    for (int v = tid; v < NGRAPH; v += 256) out[v] = hist[v];
}

// ---------------------------------------------------------------------------
// K1b: per-graph: deg = sum of 4 chunk hists -> dinv; exclusive scan ->
//      row_start; per-chunk absolute cursors -> ccur. one block per graph.
// ---------------------------------------------------------------------------
__global__ __launch_bounds__(256) void scan_graph(const int* __restrict__ chist,
                                                  int* __restrict__ ccur,
                                                  float* __restrict__ dinv,
                                                  int* __restrict__ row_start)
{
    __shared__ int cs0[NGRAPH], cs1[NGRAPH], cs2[NGRAPH];
    __shared__ int hist[NGRAPH];
    __shared__ int csA[256];
    __shared__ int csB[256];
    const int b = (blockIdx.x & 7) * 8 + (blockIdx.x >> 3);   // XCD-local graph
    const int tid = threadIdx.x;
    const int base_n = b * NGRAPH, base_e = b * EGRAPH;
    const int* ch = chist + (size_t)b * NCHUNK * NGRAPH;

    for (int v = tid; v < NGRAPH; v += 256) {
        int c0 = ch[v];
        int c1 = ch[NGRAPH + v];
        int c2 = ch[2 * NGRAPH + v];
        int c3 = ch[3 * NGRAPH + v];
        cs0[v] = c0; cs1[v] = c1; cs2[v] = c2;
        int tot = c0 + c1 + c2 + c3;
        hist[v] = tot;
        dinv[base_n + v] = rsqrtf((float)(tot + 1));   // +1 self-loop
    }
    __syncthreads();
    if (tid < 250) {
        int s = 0;
        #pragma unroll
        for (int i = 0; i < 8; ++i) s += hist[tid * 8 + i];
        csA[tid] = s;
    }
    __syncthreads();
    int* sb = csA; int* db = csB;
    for (int off = 1; off < 256; off <<= 1) {
        int v = 0;
        if (tid < 250) { v = sb[tid]; if (tid >= off) v += sb[tid - off]; }
        if (tid < 250) db[tid] = v;
        __syncthreads();
        int* t = sb; sb = db; db = t;
    }
    if (tid < 250) {
        int run = (tid == 0) ? 0 : sb[tid - 1];
        #pragma unroll
        for (int i = 0; i < 8; ++i) {
            int idx = tid * 8 + i;
            int c = hist[idx];
            hist[idx] = run;            // overwrite count with exclusive prefix
            run += c;
        }
    }
    __syncthreads();
    int* cc = ccur + (size_t)b * NCHUNK * NGRAPH;
    for (int v = tid; v < NGRAPH; v += 256) {
        int b0 = base_e + hist[v];
        row_start[base_n + v] = b0;
        int c0 = cs0[v], c1 = cs1[v], c2 = cs2[v];
        cc[v] = b0;
        cc[NGRAPH + v] = b0 + c0;
        cc[2 * NGRAPH + v] = b0 + c0 + c1;
        cc[3 * NGRAPH + v] = b0 + c0 + c1 + c2;
    }
}

// ---------------------------------------------------------------------------
// K1c: scatter src into CSR slots using private LDS cursors (no global
// atomics). 4 blocks/graph x 256 threads, XCD-local.
// ---------------------------------------------------------------------------
__global__ __launch_bounds__(256) void scatter_csr(const int* __restrict__ ei,
                                                   const int* __restrict__ ccur,
                                                   int* __restrict__ csr)
{
    __shared__ int cur[NGRAPH];
    const int lb = blockIdx.x;
    const int xcd = lb & 7, t = lb >> 3;
    const int g = xcd * 8 + (t >> 2);
    const int q = t & 3;
    const int tid = threadIdx.x;
    const int base_e = g * EGRAPH + q * CHUNK_E;
    const int base_n = g * NGRAPH;
    const int* cc = ccur + (size_t)(g * NCHUNK + q) * NGRAPH;
    for (int v = tid; v < NGRAPH; v += 256) cur[v] = cc[v];
    __syncthreads();
    for (int k = tid; k < CHUNK_E; k += 256) {
        int s = ei[base_e + k];
        int d = ei[NE + base_e + k];
        int pos = atomicAdd(&cur[d - base_n], 1);   // LDS atomic
        csr[pos] = s;
    }
}

// ---------------------------------------------------------------------------
// K2: embW = emb @ W1   (10000x64 @ 64x32)
// ---------------------------------------------------------------------------
__global__ __launch_bounds__(256) void embw_kernel(const float* __restrict__ emb,
                                                   const float* __restrict__ W1,
                                                   float* __restrict__ embW)
{
    __shared__ float W1s[EMBD * G1D];
    for (int i = threadIdx.x; i < EMBD * G1D; i += 256) W1s[i] = W1[i];
    __syncthreads();
    int id = blockIdx.x * 256 + threadIdx.x;
    int r = id >> 5, c = id & 31;
    if (r >= FEAT) return;
    const float* er = emb + r * EMBD;
    float acc = 0.f;
    #pragma unroll 8
    for (int k = 0; k < EMBD; ++k) acc += er[k] * W1s[k * G1D + c];
    embW[r * G1D + c] = acc;
}

// ---------------------------------------------------------------------------
// K3: A'[v] = dinv[v] * embW[x[v]]   (float4 lanes: 8 lanes per node)
// ---------------------------------------------------------------------------
__global__ __launch_bounds__(256) void gather_kernel(const int* __restrict__ x,
                                                     const float* __restrict__ embW,
                                                     const float* __restrict__ dinv,
                                                     float* __restrict__ A)
{
    int id = blockIdx.x * 256 + threadIdx.x;   // id = v*8 + r
    int v = id >> 3, r = id & 7;
    int xv = x[v];
    float dv = dinv[v];
    float4 e = ((const float4*)(embW + (size_t)xv * G1D))[r];
    e.x *= dv; e.y *= dv; e.z *= dv; e.w *= dv;
    ((float4*)(A + (size_t)v * G1D))[r] = e;
}

// ---------------------------------------------------------------------------
// agg: half-wave (32 lanes) per node, 4 edge-slots x 8 lanes x float4,
// 2-deep pipelined edge loop (8 edges in flight per half-wave).
// XCD swizzle: blockIdx%8 -> XCD -> graphs [xcd*8, xcd*8+8).
// ---------------------------------------------------------------------------

// K4: layer-1 aggregation + ReLU + (h1 @ W2) * dinv -> B'
__global__ __launch_bounds__(256) void agg1_kernel(const float* __restrict__ Ain,
                                                   const float* __restrict__ dinv,
                                                   const int* __restrict__ row_start,
                                                   const int* __restrict__ csr,
                                                   const float* __restrict__ b1,
                                                   const float* __restrict__ W2,
                                                   float* __restrict__ Bout)
{
    __shared__ float W2s[G1D * G2D];
    for (int i = threadIdx.x; i < G1D * G2D; i += 256) W2s[i] = W2[i];
    __syncthreads();
    const int lb = blockIdx.x;
    const int xcd = lb & 7, idx = lb >> 3;
    const int b = xcd * 8 + (idx >> 5);     // graph
    const int blk = idx & 31;
    const int half = threadIdx.x >> 5;      // 0..7
    const int hl = threadIdx.x & 31;        // lane in half-wave
    const int slot = hl >> 3;               // 0..3 edge slot
    const int r = hl & 7;                   // column quad: cols 4r..4r+3
    const int base_n = b * NGRAPH;
    const float4 bias4 = ((const float4*)b1)[r];

    for (int i = 0; i < 8; ++i) {
        int vloc = blk * 64 + half * 8 + i;
        if (vloc >= NGRAPH) break;
        int v = base_n + vloc;
        int rs = row_start[v];
        int re = (v == NN - 1) ? NE : row_start[v + 1];
        float4 acc0 = make_float4(0.f, 0.f, 0.f, 0.f);
        float4 acc1 = make_float4(0.f, 0.f, 0.f, 0.f);
        if (slot == 0)
            acc0 = ((const float4*)(Ain + (size_t)v * G1D))[r];   // self-loop
        int j = rs + slot;
        int s0 = (j < re) ? csr[j] : 0;
        int s1 = (j + 4 < re) ? csr[j + 4] : 0;
        while (j < re) {
            int jn = j + 8;
            int t0 = (jn < re) ? csr[jn] : 0;        // 2-ahead prefetch
            int t1 = (jn + 4 < re) ? csr[jn + 4] : 0;
            float4 a0 = ((const float4*)(Ain + (size_t)s0 * G1D))[r];
            float4 a1 = ((const float4*)(Ain + (size_t)s1 * G1D))[r];
            bool p1 = (j + 4) < re;
            acc0.x += a0.x; acc0.y += a0.y; acc0.z += a0.z; acc0.w += a0.w;
            acc1.x += p1 ? a1.x : 0.f;
            acc1.y += p1 ? a1.y : 0.f;
            acc1.z += p1 ? a1.z : 0.f;
            acc1.w += p1 ? a1.w : 0.f;
            j = jn; s0 = t0; s1 = t1;
        }
        float4 acc;
        acc.x = acc0.x + acc1.x;
        acc.y = acc0.y + acc1.y;
        acc.z = acc0.z + acc1.z;
        acc.w = acc0.w + acc1.w;
        #pragma unroll
        for (int off = 8; off <= 16; off <<= 1) {
            acc.x += __shfl_xor(acc.x, off, 32);
            acc.y += __shfl_xor(acc.y, off, 32);
            acc.z += __shfl_xor(acc.z, off, 32);
            acc.w += __shfl_xor(acc.w, off, 32);
        }
        float dv = dinv[v];
        float4 h4;
        h4.x = fmaxf(dv * acc.x + bias4.x, 0.f);
        h4.y = fmaxf(dv * acc.y + bias4.y, 0.f);
        h4.z = fmaxf(dv * acc.z + bias4.z, 0.f);
        h4.w = fmaxf(dv * acc.w + bias4.w, 0.f);
        float o = 0.f;
        #pragma unroll
        for (int k = 0; k < G1D; ++k) {
            float hk;
            switch (k & 3) {
                case 0: hk = __shfl(h4.x, k >> 2, 32); break;
                case 1: hk = __shfl(h4.y, k >> 2, 32); break;
                case 2: hk = __shfl(h4.z, k >> 2, 32); break;
                default: hk = __shfl(h4.w, k >> 2, 32); break;
            }
            o += hk * W2s[k * G2D + hl];
        }
        Bout[(size_t)v * G2D + hl] = dv * o;
    }
}

// K5: layer-2 aggregation + ReLU -> h2 ; score = tanh(h2 . pw / ||pw||)
__global__ __launch_bounds__(256) void agg2_kernel(const float* __restrict__ Bin,
                                                   const float* __restrict__ dinv,
                                                   const int* __restrict__ row_start,
                                                   const int* __restrict__ csr,
                                                   const float* __restrict__ b2,
                                                   const float* __restrict__ pool_w,
                                                   float* __restrict__ h2out,
                                                   float* __restrict__ scores)
{
    const int lb = blockIdx.x;
    const int xcd = lb & 7, idx = lb >> 3;
    const int b = xcd * 8 + (idx >> 5);
    const int blk = idx & 31;
    const int half = threadIdx.x >> 5;
    const int hl = threadIdx.x & 31;
    const int slot = hl >> 3;
    const int r = hl & 7;
    const int base_n = b * NGRAPH;
    const float4 bias4 = ((const float4*)b2)[r];
    const float4 pw4 = ((const float4*)pool_w)[r];

    float pw = pool_w[hl];
    float nsq = pw * pw;
    #pragma unroll
    for (int off = 16; off; off >>= 1) nsq += __shfl_xor(nsq, off, 32);
    const float inv_norm = rsqrtf(nsq);

    for (int i = 0; i < 8; ++i) {
        int vloc = blk * 64 + half * 8 + i;
        if (vloc >= NGRAPH) break;
        int v = base_n + vloc;
        int rs = row_start[v];
        int re = (v == NN - 1) ? NE : row_start[v + 1];
        float4 acc0 = make_float4(0.f, 0.f, 0.f, 0.f);
        float4 acc1 = make_float4(0.f, 0.f, 0.f, 0.f);
        if (slot == 0)
            acc0 = ((const float4*)(Bin + (size_t)v * G2D))[r];
        int j = rs + slot;
        int s0 = (j < re) ? csr[j] : 0;
        int s1 = (j + 4 < re) ? csr[j + 4] : 0;
        while (j < re) {
            int jn = j + 8;
            int t0 = (jn < re) ? csr[jn] : 0;
            int t1 = (jn + 4 < re) ? csr[jn + 4] : 0;
            float4 a0 = ((const float4*)(Bin + (size_t)s0 * G2D))[r];
            float4 a1 = ((const float4*)(Bin + (size_t)s1 * G2D))[r];
            bool p1 = (j + 4) < re;
            acc0.x += a0.x; acc0.y += a0.y; acc0.z += a0.z; acc0.w += a0.w;
            acc1.x += p1 ? a1.x : 0.f;
            acc1.y += p1 ? a1.y : 0.f;
            acc1.z += p1 ? a1.z : 0.f;
            acc1.w += p1 ? a1.w : 0.f;
            j = jn; s0 = t0; s1 = t1;
        }
        float4 acc;
        acc.x = acc0.x + acc1.x;
        acc.y = acc0.y + acc1.y;
        acc.z = acc0.z + acc1.z;
        acc.w = acc0.w + acc1.w;
        #pragma unroll
        for (int off = 8; off <= 16; off <<= 1) {
            acc.x += __shfl_xor(acc.x, off, 32);
            acc.y += __shfl_xor(acc.y, off, 32);
            acc.z += __shfl_xor(acc.z, off, 32);
            acc.w += __shfl_xor(acc.w, off, 32);
        }
        float dv = dinv[v];
        float4 h4;
        h4.x = fmaxf(dv * acc.x + bias4.x, 0.f);
        h4.y = fmaxf(dv * acc.y + bias4.y, 0.f);
        h4.z = fmaxf(dv * acc.z + bias4.z, 0.f);
        h4.w = fmaxf(dv * acc.w + bias4.w, 0.f);
        if (slot == 0)
            ((float4*)(h2out + (size_t)v * G2D))[r] = h4;
        float t = h4.x * pw4.x + h4.y * pw4.y + h4.z * pw4.z + h4.w * pw4.w;
        t += __shfl_xor(t, 1, 32);
        t += __shfl_xor(t, 2, 32);
        t += __shfl_xor(t, 4, 32);
        if (hl == 0) scores[v] = tanhf(t * inv_norm);
    }
}

// ---------------------------------------------------------------------------
// K6: per-graph top-K(1600 of 2000) via 4-pass radix-256 select + parallel
// scaled max-pool + dense MLP. one block per graph, 256 threads.
// ---------------------------------------------------------------------------
__global__ __launch_bounds__(256) void topk_pool_mlp(const float* __restrict__ h2,
                                                     const float* __restrict__ scores,
                                                     const float* __restrict__ dense_W,
                                                     const float* __restrict__ dense_b,
                                                     const float* __restrict__ out_W,
                                                     const float* __restrict__ out_b,
                                                     float* __restrict__ out)
{
    __shared__ unsigned keys[NGRAPH];
    __shared__ float    sval[NGRAPH];
    __shared__ unsigned char inc[NGRAPH];
    __shared__ int  hist[256];
    __shared__ int  csA[256];
    __shared__ int  csB[256];
    __shared__ int  sel[2];              // [0]=d*, [1]=count strictly above d*
    __shared__ int  redc[4];
    __shared__ float redf[32][32];
    __shared__ float gvec[32];
    __shared__ float dvec[DENSED];
    const int b = (blockIdx.x & 7) * 8 + (blockIdx.x >> 3);   // XCD-local graph
    const int tid = threadIdx.x;
    const int base_n = b * NGRAPH;

    for (int v = tid; v < NGRAPH; v += 256) {
        float f = scores[base_n + v];
        sval[v] = f;
        unsigned u = __float_as_uint(f);
        keys[v] = (u & 0x80000000u) ? ~u : (u | 0x80000000u);  // monotone map
    }
    __syncthreads();

    // ---- radix-256 selection of K-th largest key: 4 passes, 8 bits each ----
    unsigned T = 0;
    int need = KSEL;
    #pragma unroll
    for (int pass = 0; pass < 4; ++pass) {
        const int s = 24 - pass * 8;
        const unsigned hi_mask = (pass == 0) ? 0u : (0xFFFFFFFFu << (s + 8));
        hist[tid] = 0;
        __syncthreads();
        for (int v = tid; v < NGRAPH; v += 256) {
            unsigned k = keys[v];
            if ((k & hi_mask) == (T & hi_mask))
                atomicAdd(&hist[(k >> s) & 255], 1);
        }
        __syncthreads();
        // inclusive prefix scan of reversed hist -> suffix sums
        csA[tid] = hist[255 - tid];
        __syncthreads();
        int* sb = csA; int* db = csB;
        for (int off = 1; off < 256; off <<= 1) {
            int val = sb[tid];
            if (tid >= off) val += sb[tid - off];
            db[tid] = val;
            __syncthreads();
            int* t = sb; sb = db; db = t;
        }
        // suf[d] = sb[255-d]; d* = max d with suf[d] >= need
        {
            const int d = tid;
            int suf_d = sb[255 - d];
            int suf_d1 = (d == 255) ? 0 : sb[254 - d];
            if (suf_d >= need && suf_d1 < need) {
                sel[0] = d;
                sel[1] = suf_d1;      // elements strictly above byte d
            }
        }
        __syncthreads();
        T |= ((unsigned)sel[0]) << s;
        need -= sel[1];
        __syncthreads();
    }

    // ---- tie handling (same semantics as before) ----
    const int wid = tid >> 6, ln = tid & 63;
    int cg = 0, ce = 0;
    for (int v = tid; v < NGRAPH; v += 256) {
        cg += (keys[v] > T) ? 1 : 0;
        ce += (keys[v] == T) ? 1 : 0;
    }
    int packed = (cg << 16) | ce;
    #pragma unroll
    for (int off = 32; off; off >>= 1) packed += __shfl_down(packed, off, 64);
    if (ln == 0) redc[wid] = packed;
    __syncthreads();
    int tot = redc[0] + redc[1] + redc[2] + redc[3];
    int m_gt = tot >> 16, m_eq = tot & 0xffff;
    int needed = KSEL - m_gt;
    float fT = (T & 0x80000000u) ? __uint_as_float(T & 0x7fffffffu)
                                 : __uint_as_float(~T);
    if (m_eq == needed || fT == 0.0f) {
        // unique cutoff multiplicity, or ties at exactly 0 (contribute 0*h2=0)
        for (int v = tid; v < NGRAPH; v += 256) inc[v] = (keys[v] >= T) ? 1 : 0;
    } else {
        if (tid == 0) {
            int take = 0;
            for (int v = 0; v < NGRAPH; ++v) {
                unsigned k = keys[v];
                if (k > T) inc[v] = 1;
                else if (k == T && take < needed) { inc[v] = 1; ++take; }
                else inc[v] = 0;
            }
        }
    }
    __syncthreads();

    // ---- pooled max: g[c] = max_{v in sel} score[v]*h2[v][c], parallel ----
    {
        const int rowslot = tid >> 3;       // 0..31
        const int c4 = tid & 7;             // float4 column
        float4 m4 = make_float4(-INFINITY, -INFINITY, -INFINITY, -INFINITY);
        for (int v = rowslot; v < NGRAPH; v += 32) {
            float4 hrow = ((const float4*)(h2 + (size_t)(base_n + v) * G2D))[c4];
            float sv = inc[v] ? sval[v] : 0.f;
            float big = inc[v] ? 0.f : -INFINITY;   // excluded -> -INF
            m4.x = fmaxf(m4.x, sv * hrow.x + big);
            m4.y = fmaxf(m4.y, sv * hrow.y + big);
            m4.z = fmaxf(m4.z, sv * hrow.z + big);
            m4.w = fmaxf(m4.w, sv * hrow.w + big);
        }
        redf[rowslot][c4 * 4 + 0] = m4.x;
        redf[rowslot][c4 * 4 + 1] = m4.y;
        redf[rowslot][c4 * 4 + 2] = m4.z;
        redf[rowslot][c4 * 4 + 3] = m4.w;
    }
    __syncthreads();
    if (tid < 32) {
        float g = redf[0][tid];
        #pragma unroll
        for (int rr = 1; rr < 32; ++rr) g = fmaxf(g, redf[rr][tid]);
        gvec[tid] = g;
    }
    __syncthreads();
    if (tid < DENSED) {
        float t = dense_b[tid];
        #pragma unroll
        for (int k = 0; k < G2D; ++k) t += gvec[k] * dense_W[k * DENSED + tid];
        dvec[tid] = fmaxf(t, 0.f);
    }
    __syncthreads();
    if (tid < NCLSD) {
        float o = out_b[tid];
        #pragma unroll
        for (int j = 0; j < DENSED; ++j) o += dvec[j] * out_W[j * NCLSD + tid];
        out[b * NCLSD + tid] = o;
    }
}

// ---------------------------------------------------------------------------
extern "C" void kernel_launch(void* const* d_in, const int* in_sizes, int n_in,
                              void* d_out, int out_size, void* d_ws, size_t ws_size,
                              hipStream_t stream)
{
    (void)in_sizes; (void)n_in; (void)out_size; (void)ws_size;
    const int*   x       = (const int*)  d_in[0];
    const int*   edge    = (const int*)  d_in[1];
    const float* emb     = (const float*)d_in[3];
    const float* W1      = (const float*)d_in[4];
    const float* b1      = (const float*)d_in[5];
    const float* W2      = (const float*)d_in[6];
    const float* b2      = (const float*)d_in[7];
    const float* pool_w  = (const float*)d_in[8];
    const float* dense_W = (const float*)d_in[9];
    const float* dense_b = (const float*)d_in[10];
    const float* out_W   = (const float*)d_in[11];
    const float* out_b   = (const float*)d_in[12];
    float* outp = (float*)d_out;

    // workspace carve-up (~53 MB)
    float* embW      = (float*)d_ws;                 // FEAT*32
    float* Abuf      = embW + FEAT * G1D;            // N*32 (A' then h2)
    float* Bbuf      = Abuf + (size_t)NN * G1D;      // N*32 (B')
    float* dinv      = Bbuf + (size_t)NN * G2D;      // N
    int*   row_start = (int*)(dinv + NN);            // N
    int*   csr       = row_start + NN;               // E
    float* scores    = (float*)(csr + NE);           // N

    // CSR-build scratch inside Bbuf (consumed before agg1 writes Bbuf):
    int* chist = (int*)Bbuf;                         // NB*4*NGRAPH = 512000
    int* ccur  = chist + NB * NCHUNK * NGRAPH;       // NB*4*NGRAPH = 512000

    chunk_hist<<<NB * NCHUNK, 256, 0, stream>>>(edge, chist);
    scan_graph<<<NB, 256, 0, stream>>>(chist, ccur, dinv, row_start);
    scatter_csr<<<NB * NCHUNK, 256, 0, stream>>>(edge, ccur, csr);
    embw_kernel<<<(FEAT * G1D) / 256, 256, 0, stream>>>(emb, W1, embW);
    gather_kernel<<<(NN * 8) / 256, 256, 0, stream>>>(x, embW, dinv, Abuf);
    agg1_kernel<<<NB * 32, 256, 0, stream>>>(Abuf, dinv, row_start, csr, b1, W2, Bbuf);
    agg2_kernel<<<NB * 32, 256, 0, stream>>>(Bbuf, dinv, row_start, csr, b2, pool_w, Abuf, scores);
    topk_pool_mlp<<<NB, 256, 0, stream>>>(Abuf, scores, dense_W, dense_b, out_W, out_b, outp);
}